// Round 7
// baseline (2240.046 us; speedup 1.0000x reference)
//
#include <hip/hip_runtime.h>
#include <hip/hip_bf16.h>
#include <math.h>

typedef __hip_bfloat16 bf16;

static constexpr int B_ = 4;
static constexpr int C_ = 64;
static constexpr int H_ = 256;
static constexpr int W_ = 256;
static constexpr int P_ = H_ * W_;    // 65536
static constexpr int NP_ = B_ * P_;   // 262144

// LDS halo stride in u32 (padded odd: 60 -> 8-way conflict, 61 -> ~2-way free)
static constexpr int HSTR = 61;

__device__ __forceinline__ float cvt(float x) { return x; }
__device__ __forceinline__ float cvt(bf16 x) { return __bfloat162float(x); }
__device__ __forceinline__ float geluf(float x) { return 0.5f * x * (1.0f + erff(x * 0.70710678118654752f)); }
__device__ __forceinline__ float sigm(float x) { return 1.0f / (1.0f + __expf(-x)); }

// dtype-adaptive input load: bf=true -> bf16, else fp32
__device__ __forceinline__ float ldin(const void* p, int i, bool bf) {
    return bf ? __bfloat162float(((const bf16*)p)[i]) : ((const float*)p)[i];
}

// unpack two bf16 packed in a u32 (little endian: a = low half)
__device__ __forceinline__ void bf2x(unsigned u, float& a, float& b) {
    a = __uint_as_float(u << 16);
    b = __uint_as_float(u & 0xffff0000u);
}
__device__ __forceinline__ float bflo(unsigned u) { return __uint_as_float(u << 16); }
__device__ __forceinline__ float bfhi(unsigned u) { return __uint_as_float(u & 0xffff0000u); }
__device__ __forceinline__ unsigned bfpack(float a, float b) {
    union { unsigned u; bf16 h[2]; } pk;
    pk.h[0] = __float2bfloat16(a);
    pk.h[1] = __float2bfloat16(b);
    return pk.u;
}

// XCD-chunked remap for the 4096-block window kernels: consecutive logical
// windows land on the same XCD so halo-sharing lines hit the same L2.
__device__ __forceinline__ int win_swz(int bid) { return (bid & 7) * 512 + (bid >> 3); }

// ---------------- dtype detector ----------------
__global__ __launch_bounds__(256) void k_detect(const unsigned int* __restrict__ x, int* __restrict__ flag) {
    __shared__ int red[256];
    int cnt = 0;
    for (int i = threadIdx.x; i < 4096; i += 256) {
        unsigned int u = x[i];
        unsigned int e = (u >> 7) & 0xFFu;
        cnt += (e >= 100u && e <= 140u) ? 1 : 0;
    }
    red[threadIdx.x] = cnt;
    __syncthreads();
    for (int s = 128; s > 0; s >>= 1) {
        if (threadIdx.x < s) red[threadIdx.x] += red[threadIdx.x + s];
        __syncthreads();
    }
    if (threadIdx.x == 0) flag[0] = (red[0] > 2048) ? 1 : 0;
}

// ---------------- head: LN(x) -> conv1 -> Y ; gelu(mb1 @ Y) -> T1 ----------------
__global__ __launch_bounds__(256) void k_head(const void* __restrict__ x,
                                              const void* __restrict__ lnw, const void* __restrict__ lnb,
                                              const void* __restrict__ w1, const void* __restrict__ b1,
                                              const void* __restrict__ w2, const void* __restrict__ b2,
                                              float* __restrict__ Y, bf16* __restrict__ T1,
                                              const int* __restrict__ dtf) {
    const bool bf = dtf[0] != 0;
    __shared__ bf16 s1[4096], s2[4096];
    __shared__ float sb1[64], sb2[64], slw[64], slb[64];
    for (int i = threadIdx.x; i < 4096; i += 256) {
        s1[i] = __float2bfloat16(ldin(w1, i, bf));
        s2[i] = __float2bfloat16(ldin(w2, i, bf));
    }
    if (threadIdx.x < 64) {
        sb1[threadIdx.x] = ldin(b1, threadIdx.x, bf);
        sb2[threadIdx.x] = ldin(b2, threadIdx.x, bf);
        slw[threadIdx.x] = ldin(lnw, threadIdx.x, bf);
        slb[threadIdx.x] = ldin(lnb, threadIdx.x, bf);
    }
    __syncthreads();
    int g = blockIdx.x * 256 + threadIdx.x;
    int bb = g >> 16, p = g & (P_ - 1);
    int base = bb * 64 * P_ + p;
    float v[64];
    float mu = 0.f;
#pragma unroll
    for (int c = 0; c < 64; ++c) { v[c] = ldin(x, base + c * P_, bf); mu += v[c]; }
    mu *= (1.0f / 64.0f);
    float var = 0.f;
#pragma unroll
    for (int c = 0; c < 64; ++c) { float d = v[c] - mu; var += d * d; }
    float inv = rsqrtf(var * (1.0f / 64.0f) + 1e-6f);
#pragma unroll
    for (int c = 0; c < 64; ++c) v[c] = (v[c] - mu) * inv * slw[c] + slb[c];
    float y[64];
    const unsigned* u1 = (const unsigned*)s1;
    for (int o = 0; o < 64; ++o) {
        float a = sb1[o];
#pragma unroll
        for (int cc = 0; cc < 32; ++cc) {
            float wa, wb;
            bf2x(u1[o * 32 + cc], wa, wb);
            a = fmaf(wa, v[2 * cc], fmaf(wb, v[2 * cc + 1], a));
        }
        y[o] = a;
        Y[base + o * P_] = a;
    }
    const unsigned* u2 = (const unsigned*)s2;
    for (int o = 0; o < 64; ++o) {
        float a = sb2[o];
#pragma unroll
        for (int cc = 0; cc < 32; ++cc) {
            float wa, wb;
            bf2x(u2[o * 32 + cc], wa, wb);
            a = fmaf(wa, y[2 * cc], fmaf(wb, y[2 * cc + 1], a));
        }
        T1[base + o * P_] = __float2bfloat16(geluf(a));
    }
}

// ---------------- per-pixel channel LayerNorm -> bf16 (fp32 ws input) ----------------
__global__ __launch_bounds__(256) void k_ln(const float* __restrict__ in,
                                            const void* __restrict__ w,
                                            const void* __restrict__ b,
                                            bf16* __restrict__ out, float eps,
                                            const int* __restrict__ dtf) {
    const bool bf = dtf[0] != 0;
    __shared__ float swt[C_], sbt[C_];
    if (threadIdx.x < C_) {
        swt[threadIdx.x] = ldin(w, threadIdx.x, bf);
        sbt[threadIdx.x] = ldin(b, threadIdx.x, bf);
    }
    __syncthreads();
    int g = blockIdx.x * 256 + threadIdx.x;
    int bb = g >> 16;
    int p = g & (P_ - 1);
    int base = bb * C_ * P_ + p;
    float v[C_];
    float mu = 0.f;
#pragma unroll
    for (int c = 0; c < C_; ++c) { v[c] = in[base + c * P_]; mu += v[c]; }
    mu *= (1.0f / C_);
    float var = 0.f;
#pragma unroll
    for (int c = 0; c < C_; ++c) { float d = v[c] - mu; var += d * d; }
    var *= (1.0f / C_);
    float inv = rsqrtf(var + eps);
#pragma unroll
    for (int c = 0; c < C_; ++c)
        out[base + c * P_] = __float2bfloat16((v[c] - mu) * inv * swt[c] + sbt[c]);
}

// ---------------- fused per-pixel LN (eps 1e-6) + 1x1 projection -> bf16 ----------------
template <int COUT>
__global__ __launch_bounds__(256) void k_pwln(const float* __restrict__ Yin,
                                              const void* __restrict__ lnw, const void* __restrict__ lnb,
                                              const void* __restrict__ w,
                                              bf16* __restrict__ out,
                                              const int* __restrict__ dtf) {
    const bool bf = dtf[0] != 0;
    __shared__ bf16 swb[COUT * 64];
    __shared__ float slw[64], slb[64];
    for (int i = threadIdx.x; i < COUT * 64; i += 256) swb[i] = __float2bfloat16(ldin(w, i, bf));
    if (threadIdx.x < 64) {
        slw[threadIdx.x] = ldin(lnw, threadIdx.x, bf);
        slb[threadIdx.x] = ldin(lnb, threadIdx.x, bf);
    }
    __syncthreads();
    int g = blockIdx.x * 256 + threadIdx.x;
    int bb = g >> 16, p = g & (P_ - 1);
    int base = bb * 64 * P_ + p;
    float v[64];
    float mu = 0.f;
#pragma unroll
    for (int c = 0; c < 64; ++c) { v[c] = Yin[base + c * P_]; mu += v[c]; }
    mu *= (1.0f / 64.0f);
    float var = 0.f;
#pragma unroll
    for (int c = 0; c < 64; ++c) { float d = v[c] - mu; var += d * d; }
    float inv = rsqrtf(var * (1.0f / 64.0f) + 1e-6f);
#pragma unroll
    for (int c = 0; c < 64; ++c) v[c] = (v[c] - mu) * inv * slw[c] + slb[c];
    int obase = bb * COUT * P_ + p;
    const unsigned* uw = (const unsigned*)swb;
    for (int o = 0; o < COUT; ++o) {
        float a = 0.f;
#pragma unroll
        for (int cc = 0; cc < 32; ++cc) {
            float wa, wb;
            bf2x(uw[o * 32 + cc], wa, wb);
            a = fmaf(wa, v[2 * cc], fmaf(wb, v[2 * cc + 1], a));
        }
        out[obase + o * P_] = __float2bfloat16(a);
    }
}

// ---------------- MBConv dw3x3+gelu partial mean: 32 row-chunks per (b,c) plane ----------------
__global__ __launch_bounds__(256) void k_dwmean(const bf16* __restrict__ h,
                                                const void* __restrict__ dww,
                                                const void* __restrict__ dwb,
                                                float* __restrict__ part,
                                                const int* __restrict__ dtf) {
    const bool bf = dtf[0] != 0;
    __shared__ __align__(8) bf16 hsb[10 * 256];   // 5120 B
    __shared__ float red[256];
    int bid = blockIdx.x;
    int bc = bid >> 5, chunk = bid & 31;
    int c = bc & 63;
    int h0 = chunk * 8;
    int base = bc * P_;
    int tid = threadIdx.x;
    {
        const unsigned* gq = (const unsigned*)h;
        unsigned* hu = (unsigned*)hsb;
        for (int i = tid; i < 1280; i += 256) {
            int r = i >> 7, col2 = i & 127;
            int hh = h0 - 1 + r;
            unsigned v = 0u;
            if ((unsigned)hh < (unsigned)H_) v = gq[(base + hh * W_) / 2 + col2];
            hu[r * 128 + col2] = v;
        }
    }
    float w9[9];
#pragma unroll
    for (int k = 0; k < 9; ++k) w9[k] = ldin(dww, c * 9 + k, bf);
    float bv = ldin(dwb, c, bf);
    __syncthreads();
    float acc = 0.f;
#pragma unroll
    for (int k = 0; k < 8; ++k) {
        int j = tid + k * 256;          // 2048 px
        int r = j >> 8, x = j & 255;
        float s = bv;
#pragma unroll
        for (int kh = 0; kh < 3; ++kh) {
            const bf16* row = &hsb[(r + kh) * 256];
            float vm1 = (x > 0) ? cvt(row[x - 1]) : 0.f;
            float v0 = cvt(row[x]);
            float vp1 = (x < 255) ? cvt(row[x + 1]) : 0.f;
            s = fmaf(w9[kh * 3 + 0], vm1, s);
            s = fmaf(w9[kh * 3 + 1], v0, s);
            s = fmaf(w9[kh * 3 + 2], vp1, s);
        }
        acc += geluf(s);
    }
    red[tid] = acc;
    __syncthreads();
    for (int s2 = 128; s2 > 0; s2 >>= 1) {
        if (tid < s2) red[tid] += red[tid + s2];
        __syncthreads();
    }
    if (tid == 0) part[bc * 32 + chunk] = red[0];
}

// ---------------- SE MLP (reduces 32 partials per (b,c)) ----------------
__global__ __launch_bounds__(256) void k_se(const float* __restrict__ part,
                                            const void* __restrict__ w1,
                                            const void* __restrict__ w2,
                                            float* __restrict__ sfin,
                                            const int* __restrict__ dtf) {
    const bool bf = dtf[0] != 0;
    __shared__ float ssum[256];
    __shared__ float hbuf[B_ * 16];
    int t = threadIdx.x;
    {
        float a = 0.f;
#pragma unroll
        for (int k = 0; k < 32; ++k) a += part[t * 32 + k];
        ssum[t] = a * (1.0f / P_);
    }
    __syncthreads();
    if (t < B_ * 16) {
        int bb = t >> 4, j = t & 15;
        float a = 0.f;
        for (int c = 0; c < 64; ++c) a = fmaf(ssum[bb * 64 + c], ldin(w1, j * 64 + c, bf), a);
        hbuf[t] = a * sigm(a);
    }
    __syncthreads();
    int bb = t >> 6, c = t & 63;
    float a = 0.f;
    for (int j = 0; j < 16; ++j) a = fmaf(hbuf[bb * 16 + j], ldin(w2, c * 16 + j, bf), a);
    sfin[t] = sigm(a);
}

// ---------------- MBConv tail per window: dw+gelu+scale -> 1x1 (tiled) -> += Y ----------------
// LDS diet: sw2T overlays the dead halo after dw-conv -> 24832 B -> 6 blocks/CU
__global__ __launch_bounds__(256) void k_mb2w(const bf16* __restrict__ h,
                                              const void* __restrict__ dww, const void* __restrict__ dwb,
                                              const void* __restrict__ w2, const void* __restrict__ b2,
                                              const float* __restrict__ sfin,
                                              float* __restrict__ Y,
                                              const int* __restrict__ dtf) {
    const bool bf = dtf[0] != 0;
    __shared__ __align__(16) char arena[24832];
    unsigned* hsu = (unsigned*)arena;           // [64][61] u32 = 15616
    bf16* ts = (bf16*)(arena + 15616);          // [64][66] = 8448 -> 24064
    float* sdb = (float*)(arena + 24064);       // 64 f32
    float* sb2 = (float*)(arena + 24320);       // 64 f32
    float* ssc = (float*)(arena + 24576);       // 64 f32 -> 24832
    bf16* sw2T = (bf16*)arena;                  // overlay [0,8192) after dw conv
    int wid = win_swz(blockIdx.x);
    int bb = wid >> 10;
    int h0 = ((wid >> 5) & 31) * 8, w0 = (wid & 31) * 8;
    int tid = threadIdx.x;
    int cch = tid >> 2, quarter = tid & 3;
    // stage halo: 64 ch x 60 u32 (stride 61), 4 threads/ch x 15, incremental addressing
    {
        const unsigned* gq = (const unsigned*)h;
        int j = quarter * 15;
        int pr = j / 6, col = j - pr * 6;
        size_t chb = (size_t)(bb * 64 + cch) * P_;
        for (int k = 0; k < 15; ++k) {
            int hh = h0 + pr - 1;
            int wcx = w0 - 2 + 2 * col;
            unsigned v = 0u;
            if ((unsigned)hh < (unsigned)H_ && (unsigned)wcx < 255u)
                v = gq[(chb + hh * W_ + wcx) >> 1];
            hsu[cch * HSTR + j] = v;
            ++j; ++col;
            if (col == 6) { col = 0; ++pr; }
        }
    }
    float w9[9];
#pragma unroll
    for (int k = 0; k < 9; ++k) w9[k] = ldin(dww, cch * 9 + k, bf);
    if (tid < 64) {
        sdb[tid] = ldin(dwb, tid, bf);
        sb2[tid] = ldin(b2, tid, bf);
        ssc[tid] = sfin[bb * 64 + tid];
    }
    __syncthreads();
    // dw conv, pair-vectorized: channel cch, pairs p = quarter*8+k
    {
        const unsigned* mua = hsu + cch * HSTR;
        unsigned* tsu = (unsigned*)ts;
        float bv = sdb[cch];
        float sc = ssc[cch];
#pragma unroll
        for (int k = 0; k < 8; ++k) {
            int p = quarter * 8 + k;
            int t0 = 2 * p;
            int rt = t0 >> 3, ct = t0 & 7;
            float a0 = bv, a1 = bv;
#pragma unroll
            for (int kh = 0; kh < 3; ++kh) {
                int rb = (rt + kh) * 6 + (ct >> 1);
                unsigned u0 = mua[rb], u1 = mua[rb + 1], u2 = mua[rb + 2];
                float x1 = bfhi(u0);
                float x2 = bflo(u1), x3 = bfhi(u1);
                float x4 = bflo(u2);
                a0 = fmaf(w9[kh * 3 + 0], x1, fmaf(w9[kh * 3 + 1], x2, fmaf(w9[kh * 3 + 2], x3, a0)));
                a1 = fmaf(w9[kh * 3 + 0], x2, fmaf(w9[kh * 3 + 1], x3, fmaf(w9[kh * 3 + 2], x4, a1)));
            }
            tsu[cch * 33 + p] = bfpack(geluf(a0) * sc, geluf(a1) * sc);
        }
    }
    __syncthreads();
    // load out-proj weights into dead halo space
    for (int i = tid; i < 4096; i += 256) {
        int c = i >> 6, o = i & 63;
        sw2T[c * 64 + o] = __float2bfloat16(ldin(w2, o * 64 + c, bf));
    }
    __syncthreads();
    int og = tid >> 4, pg = tid & 15;
    int o0 = og * 4, p0 = pg * 4;
    float acc[4][4] = {};
    const unsigned* wt = (const unsigned*)sw2T;
    const unsigned* tt = (const unsigned*)ts;
    for (int c = 0; c < 64; ++c) {
        float w0v, w1v, w2v, w3v, t0, t1, t2, t3;
        bf2x(wt[c * 32 + (o0 >> 1)], w0v, w1v);
        bf2x(wt[c * 32 + (o0 >> 1) + 1], w2v, w3v);
        bf2x(tt[c * 33 + (p0 >> 1)], t0, t1);
        bf2x(tt[c * 33 + (p0 >> 1) + 1], t2, t3);
        acc[0][0] = fmaf(w0v, t0, acc[0][0]); acc[0][1] = fmaf(w0v, t1, acc[0][1]);
        acc[0][2] = fmaf(w0v, t2, acc[0][2]); acc[0][3] = fmaf(w0v, t3, acc[0][3]);
        acc[1][0] = fmaf(w1v, t0, acc[1][0]); acc[1][1] = fmaf(w1v, t1, acc[1][1]);
        acc[1][2] = fmaf(w1v, t2, acc[1][2]); acc[1][3] = fmaf(w1v, t3, acc[1][3]);
        acc[2][0] = fmaf(w2v, t0, acc[2][0]); acc[2][1] = fmaf(w2v, t1, acc[2][1]);
        acc[2][2] = fmaf(w2v, t2, acc[2][2]); acc[2][3] = fmaf(w2v, t3, acc[2][3]);
        acc[3][0] = fmaf(w3v, t0, acc[3][0]); acc[3][1] = fmaf(w3v, t1, acc[3][1]);
        acc[3][2] = fmaf(w3v, t2, acc[3][2]); acc[3][3] = fmaf(w3v, t3, acc[3][3]);
    }
#pragma unroll
    for (int i = 0; i < 4; ++i)
#pragma unroll
        for (int j = 0; j < 4; ++j) {
            int t = p0 + j;
            int p = (h0 + (t >> 3)) * W_ + w0 + (t & 7);
            Y[(bb * 64 + o0 + i) * P_ + p] += acc[i][j] + sb2[o0 + i];
        }
}

// ---------------- setup: compose Wq = qkvw @ q1w (fold 0.25 scale into q rows) ----------------
// WQT layout: [64 cin][96 out] bf16 ; BQ: f32[96] ; OWT: [32 cin][32 out] bf16
__global__ __launch_bounds__(256) void k_wprep(const void* __restrict__ q1w, const void* __restrict__ q1b,
                                               const void* __restrict__ qkvw, const void* __restrict__ outw,
                                               bf16* __restrict__ WQT, float* __restrict__ BQ,
                                               bf16* __restrict__ OWT,
                                               const int* __restrict__ dtf) {
    const bool bf = dtf[0] != 0;
    __shared__ float sq1[32 * 64];
    __shared__ float sqk[96 * 32];
    __shared__ float sb1[32];
    int tid = threadIdx.x;
    for (int i = tid; i < 2048; i += 256) sq1[i] = ldin(q1w, i, bf);
    for (int i = tid; i < 3072; i += 256) sqk[i] = ldin(qkvw, i, bf);
    if (tid < 32) sb1[tid] = ldin(q1b, tid, bf);
    __syncthreads();
    for (int idx = tid; idx < 6144; idx += 256) {
        int o = idx % 96, c = idx / 96;
        float a = 0.f;
        for (int k = 0; k < 32; ++k) a = fmaf(sqk[o * 32 + k], sq1[k * 64 + c], a);
        if (o < 32) a *= 0.25f;
        WQT[c * 96 + o] = __float2bfloat16(a);
    }
    if (tid < 96) {
        float a = 0.f;
        for (int k = 0; k < 32; ++k) a = fmaf(sqk[tid * 32 + k], sb1[k], a);
        if (tid < 32) a *= 0.25f;
        BQ[tid] = a;
    }
    for (int idx = tid; idx < 1024; idx += 256) {
        int o = idx >> 5, c = idx & 31;
        OWT[c * 32 + o] = __float2bfloat16(ldin(outw, o * 32 + c, bf));
    }
}

// ---------------- window self-attention (composed qkv, bf16 LDS, reg softmax) ----------------
__global__ __launch_bounds__(256, 4) void k_winattn(const bf16* __restrict__ xf,
                                                    const uint4* __restrict__ WQT,
                                                    const float* __restrict__ BQ,
                                                    const unsigned* __restrict__ OWT,
                                                    float* __restrict__ Y) {
    __shared__ __align__(16) char arena[35200];
    int wid = win_swz(blockIdx.x);
    int bb = wid >> 10;
    int h0 = ((wid >> 5) & 31) * 8, w0 = (wid & 31) * 8;
    int tid = threadIdx.x;
    // ---- stage composed weights + window (all bf16, vector ops) ----
    {
        uint4* sW4 = (uint4*)arena;
        for (int i = tid; i < 768; i += 256) sW4[i] = WQT[i];
        if (tid < 96) ((float*)(arena + 12288))[tid] = BQ[tid];
#pragma unroll
        for (int k = 0; k < 2; ++k) {
            int idx = tid + k * 256;          // 512 tasks: (c, window-row)
            int c = idx >> 3, r = idx & 7;
            const uint4 v = *(const uint4*)(xf + (size_t)(bb * 64 + c) * P_ + (h0 + r) * W_ + w0);
            *(uint4*)(arena + 12672 + c * 144 + r * 16) = v;
        }
    }
    __syncthreads();
    // ---- GEMM1: qkv[t][o] = bq[o] + sum_c W[c][o]*xf[c][t]  (96x64x64, 6x4 tiles) ----
    {
        const unsigned* uW = (const unsigned*)arena;
        const float* sbq = (const float*)(arena + 12288);
        const unsigned* uX = (const unsigned*)(arena + 12672);
        unsigned* uQw = (unsigned*)(arena + 21888);
        int og = tid >> 4, pg = tid & 15;     // o0 = og*6, t0 = pg*4
        float acc[6][4];
#pragma unroll
        for (int i = 0; i < 6; ++i) {
            float b = sbq[og * 6 + i];
#pragma unroll
            for (int j = 0; j < 4; ++j) acc[i][j] = b;
        }
        for (int c = 0; c < 64; ++c) {
            unsigned wu0 = uW[c * 48 + 3 * og];
            unsigned wu1 = uW[c * 48 + 3 * og + 1];
            unsigned wu2 = uW[c * 48 + 3 * og + 2];
            unsigned xu0 = uX[c * 36 + 2 * pg];
            unsigned xu1 = uX[c * 36 + 2 * pg + 1];
            float wv[6], xv[4];
            bf2x(wu0, wv[0], wv[1]); bf2x(wu1, wv[2], wv[3]); bf2x(wu2, wv[4], wv[5]);
            bf2x(xu0, xv[0], xv[1]); bf2x(xu1, xv[2], xv[3]);
#pragma unroll
            for (int i = 0; i < 6; ++i)
#pragma unroll
                for (int j = 0; j < 4; ++j) acc[i][j] = fmaf(wv[i], xv[j], acc[i][j]);
        }
#pragma unroll
        for (int j = 0; j < 4; ++j) {
            int t = pg * 4 + j;
#pragma unroll
            for (int k = 0; k < 3; ++k) {
                union { unsigned u; bf16 h[2]; } pk;
                pk.h[0] = __float2bfloat16(acc[2 * k][j]);
                pk.h[1] = __float2bfloat16(acc[2 * k + 1][j]);
                uQw[t * 52 + 3 * og + k] = pk.u;
            }
        }
    }
    __syncthreads();
    // ---- attention: wave = head, lane = token row; scores in registers ----
    {
        int hH = tid >> 6, lane = tid & 63;
        const unsigned* uQ = (const unsigned*)(arena + 21888);
        unsigned ow0 = OWT[tid * 2], ow1 = OWT[tid * 2 + 1];
        float qf[8];
        {
            const uint4 qv = *(const uint4*)&uQ[lane * 52 + hH * 4];
            bf2x(qv.x, qf[0], qf[1]); bf2x(qv.y, qf[2], qf[3]);
            bf2x(qv.z, qf[4], qf[5]); bf2x(qv.w, qf[6], qf[7]);
        }
        float p[64];
#pragma unroll
        for (int j = 0; j < 64; ++j) {
            const uint4 kv4 = *(const uint4*)&uQ[j * 52 + 16 + hH * 4];
            float kf[8];
            bf2x(kv4.x, kf[0], kf[1]); bf2x(kv4.y, kf[2], kf[3]);
            bf2x(kv4.z, kf[4], kf[5]); bf2x(kv4.w, kf[6], kf[7]);
            float s = 0.f;
#pragma unroll
            for (int d = 0; d < 8; ++d) s = fmaf(qf[d], kf[d], s);
            p[j] = s;
        }
        float m0 = fmaxf(p[0], p[4]), m1 = fmaxf(p[1], p[5]);
        float m2 = fmaxf(p[2], p[6]), m3 = fmaxf(p[3], p[7]);
#pragma unroll
        for (int j = 8; j < 64; j += 4) {
            m0 = fmaxf(m0, p[j]);     m1 = fmaxf(m1, p[j + 1]);
            m2 = fmaxf(m2, p[j + 2]); m3 = fmaxf(m3, p[j + 3]);
        }
        float mm = fmaxf(fmaxf(m0, m1), fmaxf(m2, m3));
        float s0 = 0.f, s1 = 0.f, s2 = 0.f, s3 = 0.f;
#pragma unroll
        for (int j = 0; j < 64; j += 4) {
            p[j] = __expf(p[j] - mm);         s0 += p[j];
            p[j + 1] = __expf(p[j + 1] - mm); s1 += p[j + 1];
            p[j + 2] = __expf(p[j + 2] - mm); s2 += p[j + 2];
            p[j + 3] = __expf(p[j + 3] - mm); s3 += p[j + 3];
        }
        float rs = 1.0f / ((s0 + s1) + (s2 + s3));
        float o[8] = {0.f, 0.f, 0.f, 0.f, 0.f, 0.f, 0.f, 0.f};
#pragma unroll
        for (int j = 0; j < 64; ++j) {
            const uint4 vv = *(const uint4*)&uQ[j * 52 + 32 + hH * 4];
            float vf[8];
            bf2x(vv.x, vf[0], vf[1]); bf2x(vv.y, vf[2], vf[3]);
            bf2x(vv.z, vf[4], vf[5]); bf2x(vv.w, vf[6], vf[7]);
#pragma unroll
            for (int d = 0; d < 8; ++d) o[d] = fmaf(p[j], vf[d], o[d]);
        }
        bf16* soa = (bf16*)(arena + 12672);
#pragma unroll
        for (int d = 0; d < 8; ++d)
            soa[(hH * 8 + d) * 68 + lane] = __float2bfloat16(o[d] * rs);
        unsigned* sow = (unsigned*)(arena + 17024);
        sow[tid * 2] = ow0; sow[tid * 2 + 1] = ow1;
    }
    __syncthreads();
    // ---- out projection 32x64x32 (2x4 tiles), += Y channels 0..31 ----
    {
        const unsigned* uOW = (const unsigned*)(arena + 17024);
        const unsigned* uOA = (const unsigned*)(arena + 12672);
        int og = tid >> 4, pg = tid & 15;     // o0 = og*2, t0 = pg*4
        float a2[2][4] = {};
        for (int c = 0; c < 32; ++c) {
            unsigned wu = uOW[c * 16 + og];
            unsigned a0 = uOA[c * 34 + 2 * pg], a1 = uOA[c * 34 + 2 * pg + 1];
            float wf0, wf1, x0, x1, x2, x3;
            bf2x(wu, wf0, wf1); bf2x(a0, x0, x1); bf2x(a1, x2, x3);
            a2[0][0] = fmaf(wf0, x0, a2[0][0]); a2[0][1] = fmaf(wf0, x1, a2[0][1]);
            a2[0][2] = fmaf(wf0, x2, a2[0][2]); a2[0][3] = fmaf(wf0, x3, a2[0][3]);
            a2[1][0] = fmaf(wf1, x0, a2[1][0]); a2[1][1] = fmaf(wf1, x1, a2[1][1]);
            a2[1][2] = fmaf(wf1, x2, a2[1][2]); a2[1][3] = fmaf(wf1, x3, a2[1][3]);
        }
#pragma unroll
        for (int i = 0; i < 2; ++i)
#pragma unroll
            for (int j = 0; j < 4; ++j) {
                int t = pg * 4 + j;
                int p2 = (h0 + (t >> 3)) * W_ + w0 + (t & 7);
                Y[((size_t)bb * 64 + og * 2 + i) * P_ + p2] += a2[i][j];
            }
    }
}

// ---------------- pointwise 1x1 conv (bf16 in -> bf16 out) ----------------
template <int CIN, int COUT>
__global__ __launch_bounds__(256) void k_pw(const bf16* __restrict__ in,
                                            const void* __restrict__ w,
                                            const void* __restrict__ bias,
                                            bf16* __restrict__ out,
                                            const int* __restrict__ dtf) {
    const bool bf = dtf[0] != 0;
    __shared__ float sw[COUT * CIN];
    __shared__ float sb[COUT];
    for (int i = threadIdx.x; i < COUT * CIN; i += 256) sw[i] = ldin(w, i, bf);
    if (threadIdx.x < COUT) sb[threadIdx.x] = bias ? ldin(bias, threadIdx.x, bf) : 0.f;
    __syncthreads();
    int g = blockIdx.x * 256 + threadIdx.x;
    int bb = g >> 16;
    int p = g & (P_ - 1);
    int ibase = bb * CIN * P_ + p;
    float v[CIN];
#pragma unroll
    for (int c = 0; c < CIN; ++c) v[c] = cvt(in[ibase + c * P_]);
    int obase = bb * COUT * P_ + p;
    for (int o = 0; o < COUT; ++o) {
        float acc = sb[o];
        const float* wr = &sw[o * CIN];
#pragma unroll
        for (int c = 0; c < CIN; ++c) acc = fmaf(wr[c], v[c], acc);
        out[obase + o * P_] = __float2bfloat16(acc);
    }
}

// ---------------- strided 3x3 conv (pad=1) ----------------
template <int CIN, int COUT, int OS, int STRIDE>
__global__ __launch_bounds__(256) void k_sconv(const bf16* __restrict__ in,
                                               const void* __restrict__ w,
                                               const void* __restrict__ bias,
                                               float* __restrict__ out,
                                               const int* __restrict__ dtf) {
    const bool bf = dtf[0] != 0;
    int g = blockIdx.x * 256 + threadIdx.x;
    int ow = g % OS;
    int oh = (g / OS) % OS;
    int oc = (g / (OS * OS)) % COUT;
    int bb = g / (OS * OS * COUT);
    float acc = ldin(bias, oc, bf);
    for (int ic = 0; ic < CIN; ++ic) {
        int ibase = (bb * CIN + ic) * P_;
        int wbase = (oc * CIN + ic) * 9;
#pragma unroll
        for (int kh = 0; kh < 3; ++kh) {
            int ih = oh * STRIDE + kh - 1;
            if ((unsigned)ih >= (unsigned)H_) continue;
#pragma unroll
            for (int kw = 0; kw < 3; ++kw) {
                int iw = ow * STRIDE + kw - 1;
                if ((unsigned)iw >= (unsigned)W_) continue;
                acc = fmaf(ldin(w, wbase + kh * 3 + kw, bf), cvt(in[ibase + ih * W_ + iw]), acc);
            }
        }
    }
    out[g] = acc;
}

// ---------------- sr-branch LN+gelu+kv ----------------
__global__ __launch_bounds__(64) void k_srkv(const float* __restrict__ x1,
                                             const void* __restrict__ lnw,
                                             const void* __restrict__ lnb,
                                             const void* __restrict__ kvw,
                                             const void* __restrict__ kvb,
                                             float* __restrict__ k1,
                                             float* __restrict__ v1,
                                             const int* __restrict__ dtf) {
    const bool bf = dtf[0] != 0;
    int tok = blockIdx.x;
    int bb = tok >> 8;
    int n = tok & 255;
    int c = threadIdx.x;
    __shared__ float sv[64];
    __shared__ float sg[64];
    float v = x1[(bb * 64 + c) * 256 + n];
    sv[c] = v;
    __syncthreads();
    float mu = 0.f;
    for (int i = 0; i < 64; ++i) mu += sv[i];
    mu *= (1.0f / 64.0f);
    float var = 0.f;
    for (int i = 0; i < 64; ++i) { float d = sv[i] - mu; var += d * d; }
    var *= (1.0f / 64.0f);
    float xn = (v - mu) * rsqrtf(var + 1e-5f) * ldin(lnw, c, bf) + ldin(lnb, c, bf);
    sg[c] = geluf(xn);
    __syncthreads();
    float acc = ldin(kvb, c, bf);
    for (int j = 0; j < 64; ++j) acc = fmaf(ldin(kvw, c * 64 + j, bf), sg[j], acc);
    int kk = c >> 5;
    int jh = (c >> 4) & 1;
    int d = c & 15;
    float* dst = kk ? v1 : k1;
    dst[((bb * 2 + jh) * 256 + n) * 16 + d] = acc;
}

// ---------------- low-res cross attention ----------------
__global__ __launch_bounds__(256) void k_xattn(const float* __restrict__ iqd,
                                               const float* __restrict__ k1,
                                               const float* __restrict__ v1,
                                               float* __restrict__ o1sp) {
    int bid = blockIdx.x;
    int iblk = bid & 3;
    int j = (bid >> 2) & 1;
    int bb = bid >> 3;
    __shared__ float sk[256 * 16];
    __shared__ float svv[256 * 16];
    int kbase = ((bb * 2 + j) * 256) * 16;
    for (int idx = threadIdx.x; idx < 4096; idx += 256) { sk[idx] = k1[kbase + idx]; svv[idx] = v1[kbase + idx]; }
    __syncthreads();
    int i = iblk * 256 + threadIdx.x;
    float q[16];
    int qbase = ((bb * 32 + (i >> 5)) * 32 + (i & 31)) * 32 + j * 16;
#pragma unroll
    for (int d = 0; d < 16; ++d) q[d] = iqd[qbase + d];
    float m = -1e30f, l = 0.f, o[16];
#pragma unroll
    for (int d = 0; d < 16; ++d) o[d] = 0.f;
    for (int n = 0; n < 256; ++n) {
        float s = 0.f;
#pragma unroll
        for (int d = 0; d < 16; ++d) s = fmaf(q[d], sk[n * 16 + d], s);
        s *= 0.25f;
        float mn = fmaxf(m, s);
        float corr = __expf(m - mn);
        float e = __expf(s - mn);
        l = l * corr + e;
#pragma unroll
        for (int d = 0; d < 16; ++d) o[d] = fmaf(o[d], corr, e * svv[n * 16 + d]);
        m = mn;
    }
    float r = 1.0f / l;
#pragma unroll
    for (int d = 0; d < 16; ++d)
        o1sp[((bb * 32 + j * 16 + d) * 32 + (i >> 5)) * 32 + (i & 31)] = o[d] * r;
}

// ---------------- cu conv (x8 upsample folded), += Y[32:64) ----------------
__global__ __launch_bounds__(256) void k_cuconv(const float* __restrict__ o1sp,
                                                const void* __restrict__ w,
                                                const void* __restrict__ bias,
                                                float* __restrict__ Y,
                                                const int* __restrict__ dtf) {
    const bool bf = dtf[0] != 0;
    __shared__ float sw[32 * 32 * 9];
    for (int i = threadIdx.x; i < 9216; i += 256) sw[i] = ldin(w, i, bf);
    __syncthreads();
    int g = blockIdx.x * 256 + threadIdx.x;
    int bb = g >> 16;
    int p = g & 65535;
    int h = p >> 8, x = p & 255;
    float acc[32];
#pragma unroll
    for (int oc = 0; oc < 32; ++oc) acc[oc] = ldin(bias, oc, bf);
    for (int ic = 0; ic < 32; ++ic) {
        int ibase = (bb * 32 + ic) * 1024;
        float v[9];
#pragma unroll
        for (int kh = 0; kh < 3; ++kh)
#pragma unroll
            for (int kw = 0; kw < 3; ++kw) {
                int hh = h + kh - 1, ww = x + kw - 1;
                v[kh * 3 + kw] = ((unsigned)hh < (unsigned)H_ && (unsigned)ww < (unsigned)W_)
                                     ? o1sp[ibase + (hh >> 3) * 32 + (ww >> 3)] : 0.f;
            }
        for (int oc = 0; oc < 32; ++oc) {
            const float* wr = &sw[(oc * 32 + ic) * 9];
            float a = acc[oc];
#pragma unroll
            for (int k = 0; k < 9; ++k) a = fmaf(wr[k], v[k], a);
            acc[oc] = a;
        }
    }
#pragma unroll
    for (int oc = 0; oc < 32; ++oc) Y[(bb * 64 + 32 + oc) * P_ + p] += acc[oc];
}

// ---------------- gcff tail: 2-pass halo (a then gate), a kept in regs, 24064 B LDS --------------
__global__ __launch_bounds__(256) void k_gcff2(const bf16* __restrict__ mid_g,
                                               const void* __restrict__ dww,
                                               const void* __restrict__ outw,
                                               float* __restrict__ Y,
                                               const int* __restrict__ dtf) {
    const bool bf = dtf[0] != 0;
    __shared__ __align__(16) char arena[24064];
    unsigned* cbu = (unsigned*)arena;           // [64][61] u32 = 15616
    bf16* ts = (bf16*)(arena + 15616);          // [64][66] = 8448 -> 24064
    bf16* sowT = (bf16*)arena;                  // overlay [0,8192) after convs
    int wid = win_swz(blockIdx.x);
    int bb = wid >> 10;
    int h0 = ((wid >> 5) & 31) * 8, w0 = (wid & 31) * 8;
    int tid = threadIdx.x;
    int cch = tid >> 2, quarter = tid & 3;
    int j0 = quarter * 15;
    int pr0 = j0 / 6, col0 = j0 - pr0 * 6;
    const unsigned* gq = (const unsigned*)mid_g;
    float areg[16];
    float w9[9];
    // ---- pass A: stage a-branch channel cch ----
    {
        int j = j0, pr = pr0, col = col0;
        size_t chb = (size_t)(bb * 128 + cch) * P_;
        for (int k = 0; k < 15; ++k) {
            int hh = h0 + pr - 1;
            int wcx = w0 - 2 + 2 * col;
            unsigned v = 0u;
            if ((unsigned)hh < (unsigned)H_ && (unsigned)wcx < 255u)
                v = gq[(chb + hh * W_ + wcx) >> 1];
            cbu[cch * HSTR + j] = v;
            ++j; ++col;
            if (col == 6) { col = 0; ++pr; }
        }
    }
#pragma unroll
    for (int k = 0; k < 9; ++k) w9[k] = ldin(dww, cch * 9 + k, bf);
    __syncthreads();
    // conv-a -> registers
    {
        const unsigned* mua = cbu + cch * HSTR;
#pragma unroll
        for (int k = 0; k < 8; ++k) {
            int p = quarter * 8 + k;
            int t0 = 2 * p;
            int rt = t0 >> 3, ct = t0 & 7;
            float a0 = 0.f, a1 = 0.f;
#pragma unroll
            for (int kh = 0; kh < 3; ++kh) {
                int rb = (rt + kh) * 6 + (ct >> 1);
                unsigned u0 = mua[rb], u1 = mua[rb + 1], u2 = mua[rb + 2];
                float x1 = bfhi(u0);
                float x2 = bflo(u1), x3 = bfhi(u1);
                float x4 = bflo(u2);
                a0 = fmaf(w9[kh * 3 + 0], x1, fmaf(w9[kh * 3 + 1], x2, fmaf(w9[kh * 3 + 2], x3, a0)));
                a1 = fmaf(w9[kh * 3 + 0], x2, fmaf(w9[kh * 3 + 1], x3, fmaf(w9[kh * 3 + 2], x4, a1)));
            }
            areg[2 * k] = a0;
            areg[2 * k + 1] = a1;
        }
    }
    __syncthreads();
    // ---- pass G: stage gate channel cch+64 into same halo buffer ----
    {
        int j = j0, pr = pr0, col = col0;
        size_t chb = (size_t)(bb * 128 + 64 + cch) * P_;
        for (int k = 0; k < 15; ++k) {
            int hh = h0 + pr - 1;
            int wcx = w0 - 2 + 2 * col;
            unsigned v = 0u;
            if ((unsigned)hh < (unsigned)H_ && (unsigned)wcx < 255u)
                v = gq[(chb + hh * W_ + wcx) >> 1];
            cbu[cch * HSTR + j] = v;
            ++j; ++col;
            if (col == 6) { col = 0; ++pr; }
        }
    }
#pragma unroll
    for (int k = 0; k < 9; ++k) w9[k] = ldin(dww, (64 + cch) * 9 + k, bf);
    __syncthreads();
    // conv-g + combine -> ts
    {
        const unsigned* mua = cbu + cch * HSTR;
        unsigned* tsu = (unsigned*)ts;
#pragma unroll
        for (int k = 0; k < 8; ++k) {
            int p = quarter * 8 + k;
            int t0 = 2 * p;
            int rt = t0 >> 3, ct = t0 & 7;
            float g0 = 0.f, g1 = 0.f;
#pragma unroll
            for (int kh = 0; kh < 3; ++kh) {
                int rb = (rt + kh) * 6 + (ct >> 1);
                unsigned u0 = mua[rb], u1 = mua[rb + 1], u2 = mua[rb + 2];
                float x1 = bfhi(u0);
                float x2 = bflo(u1), x3 = bfhi(u1);
                float x4 = bflo(u2);
                g0 = fmaf(w9[kh * 3 + 0], x1, fmaf(w9[kh * 3 + 1], x2, fmaf(w9[kh * 3 + 2], x3, g0)));
                g1 = fmaf(w9[kh * 3 + 0], x2, fmaf(w9[kh * 3 + 1], x3, fmaf(w9[kh * 3 + 2], x4, g1)));
            }
            tsu[cch * 33 + p] = bfpack(geluf(areg[2 * k]) * g0, geluf(areg[2 * k + 1]) * g1);
        }
    }
    __syncthreads();
    // load out-proj weights into dead halo space
    for (int i = tid; i < 4096; i += 256) {
        int c = i >> 6, o = i & 63;
        sowT[c * 64 + o] = __float2bfloat16(ldin(outw, o * 64 + c, bf));
    }
    __syncthreads();
    int og = tid >> 4, pg = tid & 15;
    int o0 = og * 4, p0 = pg * 4;
    float acc[4][4] = {};
    const unsigned* wt = (const unsigned*)sowT;
    const unsigned* tt = (const unsigned*)ts;
    for (int c = 0; c < 64; ++c) {
        float w0v, w1v, w2v, w3v, t0, t1, t2, t3;
        bf2x(wt[c * 32 + (o0 >> 1)], w0v, w1v);
        bf2x(wt[c * 32 + (o0 >> 1) + 1], w2v, w3v);
        bf2x(tt[c * 33 + (p0 >> 1)], t0, t1);
        bf2x(tt[c * 33 + (p0 >> 1) + 1], t2, t3);
        acc[0][0] = fmaf(w0v, t0, acc[0][0]); acc[0][1] = fmaf(w0v, t1, acc[0][1]);
        acc[0][2] = fmaf(w0v, t2, acc[0][2]); acc[0][3] = fmaf(w0v, t3, acc[0][3]);
        acc[1][0] = fmaf(w1v, t0, acc[1][0]); acc[1][1] = fmaf(w1v, t1, acc[1][1]);
        acc[1][2] = fmaf(w1v, t2, acc[1][2]); acc[1][3] = fmaf(w1v, t3, acc[1][3]);
        acc[2][0] = fmaf(w2v, t0, acc[2][0]); acc[2][1] = fmaf(w2v, t1, acc[2][1]);
        acc[2][2] = fmaf(w2v, t2, acc[2][2]); acc[2][3] = fmaf(w2v, t3, acc[2][3]);
        acc[3][0] = fmaf(w3v, t0, acc[3][0]); acc[3][1] = fmaf(w3v, t1, acc[3][1]);
        acc[3][2] = fmaf(w3v, t2, acc[3][2]); acc[3][3] = fmaf(w3v, t3, acc[3][3]);
    }
#pragma unroll
    for (int i = 0; i < 4; ++i)
#pragma unroll
        for (int j = 0; j < 4; ++j) {
            int t = p0 + j;
            int p = (h0 + (t >> 3)) * W_ + w0 + (t & 7);
            Y[(bb * 64 + o0 + i) * P_ + p] += acc[i][j];
        }
}

// ---------------- channel attention tail: owT overlays dead q-rows -> 40960 B -> 4 blocks/CU -----
__global__ __launch_bounds__(256) void k_chattn2(const bf16* __restrict__ qkv_g,
                                                 const void* __restrict__ dww,
                                                 const void* __restrict__ outw,
                                                 const void* __restrict__ tempw,
                                                 float* __restrict__ Y,
                                                 const int* __restrict__ dtf) {
    const bool bf = dtf[0] != 0;
    __shared__ __align__(16) char arena[40960];
    bf16* sq = (bf16*)arena;                 // [192][66] = 25344
    bf16* chunkb = (bf16*)(arena + 25344);   // [64][61 u32] = 15616 -> 40960
    bf16* s_owT = (bf16*)arena;              // [c][o] 8192, overlays q-rows (dead after s_att)
    float* s_att = (float*)(arena + 25344);  // [64][17] = 4352 (overlay chunkb)
    bf16* s_oc = (bf16*)(arena + 29696);     // [64][66] = 8448 (end 38144 < 40960)
    int wid = win_swz(blockIdx.x);
    int bb = wid >> 10;
    int h0 = ((wid >> 5) & 31) * 8, w0 = (wid & 31) * 8;
    int tid = threadIdx.x;
    int cch = tid >> 2, quarter = tid & 3;
    const unsigned* gq = (const unsigned*)qkv_g;
    unsigned* cbu = (unsigned*)chunkb;
    unsigned* squ = (unsigned*)sq;
    int j0 = quarter * 15;
    int pr0 = j0 / 6, col0 = j0 - pr0 * 6;
    for (int chunk = 0; chunk < 3; ++chunk) {
        int ch0 = chunk * 64;
        // stage: 64 ch x 60 u32 (stride 61), 4 threads/ch x 15
        {
            int j = j0, pr = pr0, col = col0;
            size_t chb = (size_t)((bb * 192 + ch0 + cch) * P_);
            for (int k = 0; k < 15; ++k) {
                int hh = h0 + pr - 1;
                int wcx = w0 - 2 + 2 * col;
                unsigned v = 0u;
                if ((unsigned)hh < (unsigned)H_ && (unsigned)wcx < 255u)
                    v = gq[(chb + hh * W_ + wcx) >> 1];
                cbu[cch * HSTR + j] = v;
                ++j; ++col;
                if (col == 6) { col = 0; ++pr; }
            }
        }
        float w9[9];
#pragma unroll
        for (int k = 0; k < 9; ++k) w9[k] = ldin(dww, (ch0 + cch) * 9 + k, bf);
        __syncthreads();
        // dw conv pair-vectorized: channel cch, pairs p = quarter*8+k
        {
            const unsigned* mua = cbu + cch * HSTR;
#pragma unroll
            for (int k = 0; k < 8; ++k) {
                int p = quarter * 8 + k;
                int t0 = 2 * p;
                int rt = t0 >> 3, ct = t0 & 7;
                float a0 = 0.f, a1 = 0.f;
#pragma unroll
                for (int kh = 0; kh < 3; ++kh) {
                    int rb = (rt + kh) * 6 + (ct >> 1);
                    unsigned u0 = mua[rb], u1 = mua[rb + 1], u2 = mua[rb + 2];
                    float x1 = bfhi(u0);
                    float x2 = bflo(u1), x3 = bfhi(u1);
                    float x4 = bflo(u2);
                    a0 = fmaf(w9[kh * 3 + 0], x1, fmaf(w9[kh * 3 + 1], x2, fmaf(w9[kh * 3 + 2], x3, a0)));
                    a1 = fmaf(w9[kh * 3 + 0], x2, fmaf(w9[kh * 3 + 1], x3, fmaf(w9[kh * 3 + 2], x4, a1)));
                }
                squ[(ch0 + cch) * 33 + p] = bfpack(a0, a1);
            }
        }
        __syncthreads();
    }
    // L2-normalize q and k rows (vectorized)
    if (tid < 128) {
        unsigned* row = squ + tid * 33;
        float v[64];
        float ss = 0.f;
#pragma unroll
        for (int t2 = 0; t2 < 32; ++t2) {
            bf2x(row[t2], v[2 * t2], v[2 * t2 + 1]);
            ss = fmaf(v[2 * t2], v[2 * t2], fmaf(v[2 * t2 + 1], v[2 * t2 + 1], ss));
        }
        float inv = 1.0f / fmaxf(sqrtf(ss), 1e-12f);
#pragma unroll
        for (int t2 = 0; t2 < 32; ++t2)
            row[t2] = bfpack(v[2 * t2] * inv, v[2 * t2 + 1] * inv);
    }
    __syncthreads();
    // s_att = (q . k) * temp  (vectorized along t)
    for (int i = tid; i < 1024; i += 256) {
        int hh = i >> 8, d = (i >> 4) & 15, f = i & 15;
        const unsigned* qrow = squ + (hh * 16 + d) * 33;
        const unsigned* krow = squ + (64 + hh * 16 + f) * 33;
        float acc = 0.f;
#pragma unroll
        for (int t2 = 0; t2 < 32; ++t2) {
            float q0, q1, k0, k1;
            bf2x(qrow[t2], q0, q1);
            bf2x(krow[t2], k0, k1);
            acc = fmaf(q0, k0, fmaf(q1, k1, acc));
        }
        s_att[(hh * 16 + d) * 17 + f] = acc * ldin(tempw, hh, bf);
    }
    __syncthreads();
    if (tid < 64) {
        int row = tid;
        float m = -1e30f;
        for (int f = 0; f < 16; ++f) m = fmaxf(m, s_att[row * 17 + f]);
        float sum = 0.f;
        for (int f = 0; f < 16; ++f) { float e = __expf(s_att[row * 17 + f] - m); s_att[row * 17 + f] = e; sum += e; }
        float r = 1.0f / sum;
        for (int f = 0; f < 16; ++f) s_att[row * 17 + f] *= r;
    }
    __syncthreads();
    // PV, pair-vectorized along t (reads V rows only) + owT load into dead q-row space
    {
        unsigned* s_ocu = (unsigned*)s_oc;
        for (int i = tid; i < 2048; i += 256) {
            int row = i >> 5, p = i & 31;
            int hh = row >> 4, d = row & 15;
            const float* arow = &s_att[(hh * 16 + d) * 17];
            float o0 = 0.f, o1 = 0.f;
#pragma unroll
            for (int f = 0; f < 16; ++f) {
                float av = arow[f];
                float v0, v1;
                bf2x(squ[(128 + hh * 16 + f) * 33 + p], v0, v1);
                o0 = fmaf(av, v0, o0);
                o1 = fmaf(av, v1, o1);
            }
            s_ocu[row * 33 + p] = bfpack(o0, o1);
        }
        for (int i = tid; i < 4096; i += 256) {
            int c = i >> 6, o = i & 63;
            s_owT[c * 64 + o] = __float2bfloat16(ldin(outw, o * 64 + c, bf));
        }
    }
    __syncthreads();
    int og = tid >> 4, pg = tid & 15;
    int o0 = og * 4, p0 = pg * 4;
    float acc[4][4] = {};
    const unsigned* wt = (const unsigned*)s_owT;
    const unsigned* tt = (const unsigned*)s_oc;
    for (int c = 0; c < 64; ++c) {
        float w0v, w1v, w2v, w3v, t0, t1, t2, t3;
        bf2x(wt[c * 32 + (o0 >> 1)], w0v, w1v);
        bf2x(wt[c * 32 + (o0 >> 1) + 1], w2v, w3v);
        bf2x(tt[c * 33 + (p0 >> 1)], t0, t1);
        bf2x(tt[c * 33 + (p0 >> 1) + 1], t2, t3);
        acc[0][0] = fmaf(w0v, t0, acc[0][0]); acc[0][1] = fmaf(w0v, t1, acc[0][1]);
        acc[0][2] = fmaf(w0v, t2, acc[0][2]); acc[0][3] = fmaf(w0v, t3, acc[0][3]);
        acc[1][0] = fmaf(w1v, t0, acc[1][0]); acc[1][1] = fmaf(w1v, t1, acc[1][1]);
        acc[1][2] = fmaf(w1v, t2, acc[1][2]); acc[1][3] = fmaf(w1v, t3, acc[1][3]);
        acc[2][0] = fmaf(w2v, t0, acc[2][0]); acc[2][1] = fmaf(w2v, t1, acc[2][1]);
        acc[2][2] = fmaf(w2v, t2, acc[2][2]); acc[2][3] = fmaf(w2v, t3, acc[2][3]);
        acc[3][0] = fmaf(w3v, t0, acc[3][0]); acc[3][1] = fmaf(w3v, t1, acc[3][1]);
        acc[3][2] = fmaf(w3v, t2, acc[3][2]); acc[3][3] = fmaf(w3v, t3, acc[3][3]);
    }
#pragma unroll
    for (int i = 0; i < 4; ++i)
#pragma unroll
        for (int j = 0; j < 4; ++j) {
            int t = p0 + j;
            int p = (h0 + (t >> 3)) * W_ + w0 + (t & 7);
            Y[(bb * 64 + o0 + i) * P_ + p] += acc[i][j];
        }
}

// ---------------- final 1x1 over concat([x, y]) -> adaptive dtype out ----------------
__global__ __launch_bounds__(256) void k_final(const void* __restrict__ x,
                                               const float* __restrict__ Yb,
                                               const void* __restrict__ w,
                                               const void* __restrict__ bias,
                                               void* __restrict__ out,
                                               const int* __restrict__ dtf) {
    const bool bf = dtf[0] != 0;
    __shared__ float sw[64 * 128];
    __shared__ float sb[64];
    for (int i = threadIdx.x; i < 8192; i += 256) sw[i] = ldin(w, i, bf);
    if (threadIdx.x < 64) sb[threadIdx.x] = ldin(bias, threadIdx.x, bf);
    __syncthreads();
    int g = blockIdx.x * 256 + threadIdx.x;
    int bb = g >> 16;
    int p = g & 65535;
    float xv[64], yv[64];
    int base = bb * 64 * P_ + p;
#pragma unroll
    for (int c = 0; c < 64; ++c) xv[c] = ldin(x, base + c * P_, bf);
#pragma unroll
    for (int c = 0; c < 64; ++c) yv[c] = Yb[base + c * P_];
    for (int o = 0; o < 64; ++o) {
        float acc = sb[o];
        const float* wr = &sw[o * 128];
#pragma unroll
        for (int c = 0; c < 64; ++c) acc = fmaf(wr[c], xv[c], acc);
#pragma unroll
        for (int c = 0; c < 64; ++c) acc = fmaf(wr[64 + c], yv[c], acc);
        if (bf) ((bf16*)out)[base + o * P_] = __float2bfloat16(acc);
        else    ((float*)out)[base + o * P_] = acc;
    }
}

extern "C" void kernel_launch(void* const* d_in, const int* in_sizes, int n_in,
                              void* d_out, int out_size, void* d_ws, size_t ws_size,
                              hipStream_t stream) {
    const void* x        = d_in[0];
    const void* norm_w   = d_in[1];
    const void* norm_b   = d_in[2];
    const void* conv1_w  = d_in[3];
    const void* conv1_b  = d_in[4];
    const void* conv2_w  = d_in[5];
    const void* conv2_b  = d_in[6];
    const void* mb_w1    = d_in[7];
    const void* mb_b1    = d_in[8];
    const void* mb_dw_w  = d_in[9];
    const void* mb_dw_b  = d_in[10];
    const void* se_w1    = d_in[11];
    const void* se_w2    = d_in[12];
    const void* mb_w2    = d_in[13];
    const void* mb_b2    = d_in[14];
    const void* ln_att_w = d_in[15];
    const void* ln_att_b = d_in[16];
    const void* q1_w     = d_in[17];
    const void* q1_b     = d_in[18];
    const void* qkv_w    = d_in[19];
    const void* to_out_w = d_in[20];
    const void* sr_w     = d_in[21];
    const void* sr_b     = d_in[22];
    const void* ln_sr_w  = d_in[23];
    const void* ln_sr_b  = d_in[24];
    const void* kv1_w    = d_in[25];
    const void* kv1_b    = d_in[26];
    const void* q2_w     = d_in[27];
    const void* q2_b     = d_in[28];
    const void* cd_w     = d_in[29];
    const void* cd_b     = d_in[30];
    const void* cu_w     = d_in[31];
    const void* cu_b     = d_in[32];
    const void* cln1_w   = d_in[33];
    const void* cln1_b   = d_in[34];
    const void* ff1_in_w = d_in[35];
    const void* ff1_dw_w = d_in[36];
    const void* ff1_out_w= d_in[37];
    const void* cln2_w   = d_in[38];
    const void* cln2_b   = d_in[39];
    const void* ca_temp  = d_in[40];
    const void* ca_qkv_w = d_in[41];
    const void* ca_dw_w  = d_in[42];
    const void* ca_out_w = d_in[43];
    const void* cln3_w   = d_in[44];
    const void* cln3_b   = d_in[45];
    const void* ff2_in_w = d_in[46];
    const void* ff2_dw_w = d_in[47];
    const void* ff2_out_w= d_in[48];

    // Workspace: smalls @0, Y @2M (64M), T1 @66M (32M), IQ @98M (16M), MID/QKV @114M (96M) -> 210M peak
    char* ws = (char*)d_ws;
    int*   dtf   = (int*)ws;
    float* s_fin = (float*)(ws + 8192);
    bf16*  WQT   = (bf16*)(ws + 16384);   // 64x96 bf16 composed qkv weight [c][o], 12288 B
    float* BQc   = (float*)(ws + 28672);  // 96 f32 composed bias, 384 B
    bf16*  OWT   = (bf16*)(ws + 29056);   // 32x32 bf16 out-proj [c][o], 2048 B
    float* part  = (float*)(ws + 32768);  // 256x32 dwmean partials, 32768 B
    float* iqd   = (float*)(ws + 65536);
    float* x1    = (float*)(ws + 589824);
    float* k1b   = (float*)(ws + 851968);
    float* v1b   = (float*)(ws + 983040);
    float* o1sp  = (float*)(ws + 1114112);
    float* Y     = (float*)(ws + 2097152);
    bf16*  T1    = (bf16*)(ws + 69206016);
    bf16*  IQ    = (bf16*)(ws + 102760448);
    bf16*  MIDQ  = (bf16*)(ws + 119537664);

    dim3 blk(256);
    dim3 gPix(NP_ / 256);    // 1024
    dim3 gWin(B_ * 32 * 32); // 4096

    k_detect<<<dim3(1), blk, 0, stream>>>((const unsigned int*)x, dtf);
    // compose window-attn weights (tiny, once)
    k_wprep<<<dim3(1), blk, 0, stream>>>(q1_w, q1_b, qkv_w, to_out_w, WQT, BQc, OWT, dtf);
    // LN + conv1 -> Y ; mb1+gelu -> T1
    k_head<<<gPix, blk, 0, stream>>>(x, norm_w, norm_b, conv1_w, conv1_b, mb_w1, mb_b1, Y, T1, dtf);
    // MBConv SE + tail
    k_dwmean<<<dim3(B_ * C_ * 32), blk, 0, stream>>>(T1, mb_dw_w, mb_dw_b, part, dtf);
    k_se<<<dim3(1), blk, 0, stream>>>(part, se_w1, se_w2, s_fin, dtf);
    k_mb2w<<<gWin, blk, 0, stream>>>(T1, mb_dw_w, mb_dw_b, mb_w2, mb_b2, s_fin, Y, dtf);
    // hybrid attention
    k_ln<<<gPix, blk, 0, stream>>>(Y, ln_att_w, ln_att_b, T1, 1e-5f, dtf);
    k_winattn<<<gWin, blk, 0, stream>>>(T1, (const uint4*)WQT, BQc, (const unsigned*)OWT, Y);
    // cross-attn branch
    k_pw<64, 32><<<gPix, blk, 0, stream>>>(T1, q2_w, q2_b, IQ, dtf);
    k_sconv<32, 32, 32, 8><<<dim3(512), blk, 0, stream>>>(IQ, cd_w, cd_b, iqd, dtf);
    k_sconv<64, 64, 16, 16><<<dim3(256), blk, 0, stream>>>(T1, sr_w, sr_b, x1, dtf);
    k_srkv<<<dim3(B_ * 256), dim3(64), 0, stream>>>(x1, ln_sr_w, ln_sr_b, kv1_w, kv1_b, k1b, v1b, dtf);
    k_xattn<<<dim3(32), blk, 0, stream>>>(iqd, k1b, v1b, o1sp);
    k_cuconv<<<gPix, blk, 0, stream>>>(o1sp, cu_w, cu_b, Y, dtf);
    // gcff #1 (fused LN + in-proj, then window tail)
    k_pwln<128><<<gPix, blk, 0, stream>>>(Y, cln1_w, cln1_b, ff1_in_w, MIDQ, dtf);
    k_gcff2<<<gWin, blk, 0, stream>>>(MIDQ, ff1_dw_w, ff1_out_w, Y, dtf);
    // channel attention (fused LN + qkv-proj, then window tail)
    k_pwln<192><<<gPix, blk, 0, stream>>>(Y, cln2_w, cln2_b, ca_qkv_w, MIDQ, dtf);
    k_chattn2<<<gWin, blk, 0, stream>>>(MIDQ, ca_dw_w, ca_out_w, ca_temp, Y, dtf);
    // gcff #2
    k_pwln<128><<<gPix, blk, 0, stream>>>(Y, cln3_w, cln3_b, ff2_in_w, MIDQ, dtf);
    k_gcff2<<<gWin, blk, 0, stream>>>(MIDQ, ff2_dw_w, ff2_out_w, Y, dtf);
    // fuse with block input
    k_final<<<gPix, blk, 0, stream>>>(x, Y, conv2_w, conv2_b, d_out, dtf);

    (void)in_sizes; (void)n_in; (void)out_size; (void)ws_size;
}

// Round 8
// 2120.110 us; speedup vs baseline: 1.0566x; 1.0566x over previous
//
#include <hip/hip_runtime.h>
#include <hip/hip_bf16.h>
#include <math.h>

typedef __hip_bfloat16 bf16;

static constexpr int B_ = 4;
static constexpr int C_ = 64;
static constexpr int H_ = 256;
static constexpr int W_ = 256;
static constexpr int P_ = H_ * W_;    // 65536
static constexpr int NP_ = B_ * P_;   // 262144

// LDS halo stride in u32 (padded odd: 60 -> 8-way conflict, 61 -> ~2-way free)
static constexpr int HSTR = 61;

__device__ __forceinline__ float cvt(float x) { return x; }
__device__ __forceinline__ float cvt(bf16 x) { return __bfloat162float(x); }
__device__ __forceinline__ float geluf(float x) { return 0.5f * x * (1.0f + erff(x * 0.70710678118654752f)); }
__device__ __forceinline__ float sigm(float x) { return 1.0f / (1.0f + __expf(-x)); }

// dtype-adaptive input load: bf=true -> bf16, else fp32
__device__ __forceinline__ float ldin(const void* p, int i, bool bf) {
    return bf ? __bfloat162float(((const bf16*)p)[i]) : ((const float*)p)[i];
}

// unpack two bf16 packed in a u32 (little endian: a = low half)
__device__ __forceinline__ void bf2x(unsigned u, float& a, float& b) {
    a = __uint_as_float(u << 16);
    b = __uint_as_float(u & 0xffff0000u);
}
__device__ __forceinline__ float bflo(unsigned u) { return __uint_as_float(u << 16); }
__device__ __forceinline__ float bfhi(unsigned u) { return __uint_as_float(u & 0xffff0000u); }
__device__ __forceinline__ unsigned bfpack(float a, float b) {
    union { unsigned u; bf16 h[2]; } pk;
    pk.h[0] = __float2bfloat16(a);
    pk.h[1] = __float2bfloat16(b);
    return pk.u;
}

// XCD-chunked remap for the 4096-block window kernels: consecutive logical
// windows land on the same XCD so halo-sharing lines hit the same L2.
__device__ __forceinline__ int win_swz(int bid) { return (bid & 7) * 512 + (bid >> 3); }

// ---------------- dtype detector ----------------
__global__ __launch_bounds__(256) void k_detect(const unsigned int* __restrict__ x, int* __restrict__ flag) {
    __shared__ int red[256];
    int cnt = 0;
    for (int i = threadIdx.x; i < 4096; i += 256) {
        unsigned int u = x[i];
        unsigned int e = (u >> 7) & 0xFFu;
        cnt += (e >= 100u && e <= 140u) ? 1 : 0;
    }
    red[threadIdx.x] = cnt;
    __syncthreads();
    for (int s = 128; s > 0; s >>= 1) {
        if (threadIdx.x < s) red[threadIdx.x] += red[threadIdx.x + s];
        __syncthreads();
    }
    if (threadIdx.x == 0) flag[0] = (red[0] > 2048) ? 1 : 0;
}

// ---------------- head: LN(x) -> conv1 -> Y ; gelu(mb1 @ Y) -> T1 ----------------
__global__ __launch_bounds__(256) void k_head(const void* __restrict__ x,
                                              const void* __restrict__ lnw, const void* __restrict__ lnb,
                                              const void* __restrict__ w1, const void* __restrict__ b1,
                                              const void* __restrict__ w2, const void* __restrict__ b2,
                                              float* __restrict__ Y, bf16* __restrict__ T1,
                                              const int* __restrict__ dtf) {
    const bool bf = dtf[0] != 0;
    __shared__ bf16 s1[4096], s2[4096];
    __shared__ float sb1[64], sb2[64], slw[64], slb[64];
    for (int i = threadIdx.x; i < 4096; i += 256) {
        s1[i] = __float2bfloat16(ldin(w1, i, bf));
        s2[i] = __float2bfloat16(ldin(w2, i, bf));
    }
    if (threadIdx.x < 64) {
        sb1[threadIdx.x] = ldin(b1, threadIdx.x, bf);
        sb2[threadIdx.x] = ldin(b2, threadIdx.x, bf);
        slw[threadIdx.x] = ldin(lnw, threadIdx.x, bf);
        slb[threadIdx.x] = ldin(lnb, threadIdx.x, bf);
    }
    __syncthreads();
    int g = blockIdx.x * 256 + threadIdx.x;
    int bb = g >> 16, p = g & (P_ - 1);
    int base = bb * 64 * P_ + p;
    float v[64];
    float mu = 0.f;
#pragma unroll
    for (int c = 0; c < 64; ++c) { v[c] = ldin(x, base + c * P_, bf); mu += v[c]; }
    mu *= (1.0f / 64.0f);
    float var = 0.f;
#pragma unroll
    for (int c = 0; c < 64; ++c) { float d = v[c] - mu; var += d * d; }
    float inv = rsqrtf(var * (1.0f / 64.0f) + 1e-6f);
#pragma unroll
    for (int c = 0; c < 64; ++c) v[c] = (v[c] - mu) * inv * slw[c] + slb[c];
    float y[64];
    const unsigned* u1 = (const unsigned*)s1;
    for (int o = 0; o < 64; ++o) {
        float a = sb1[o];
#pragma unroll
        for (int cc = 0; cc < 32; ++cc) {
            float wa, wb;
            bf2x(u1[o * 32 + cc], wa, wb);
            a = fmaf(wa, v[2 * cc], fmaf(wb, v[2 * cc + 1], a));
        }
        y[o] = a;
        Y[base + o * P_] = a;
    }
    const unsigned* u2 = (const unsigned*)s2;
    for (int o = 0; o < 64; ++o) {
        float a = sb2[o];
#pragma unroll
        for (int cc = 0; cc < 32; ++cc) {
            float wa, wb;
            bf2x(u2[o * 32 + cc], wa, wb);
            a = fmaf(wa, y[2 * cc], fmaf(wb, y[2 * cc + 1], a));
        }
        T1[base + o * P_] = __float2bfloat16(geluf(a));
    }
}

// ---------------- per-pixel channel LayerNorm -> bf16 (fp32 ws input) ----------------
__global__ __launch_bounds__(256) void k_ln(const float* __restrict__ in,
                                            const void* __restrict__ w,
                                            const void* __restrict__ b,
                                            bf16* __restrict__ out, float eps,
                                            const int* __restrict__ dtf) {
    const bool bf = dtf[0] != 0;
    __shared__ float swt[C_], sbt[C_];
    if (threadIdx.x < C_) {
        swt[threadIdx.x] = ldin(w, threadIdx.x, bf);
        sbt[threadIdx.x] = ldin(b, threadIdx.x, bf);
    }
    __syncthreads();
    int g = blockIdx.x * 256 + threadIdx.x;
    int bb = g >> 16;
    int p = g & (P_ - 1);
    int base = bb * C_ * P_ + p;
    float v[C_];
    float mu = 0.f;
#pragma unroll
    for (int c = 0; c < C_; ++c) { v[c] = in[base + c * P_]; mu += v[c]; }
    mu *= (1.0f / C_);
    float var = 0.f;
#pragma unroll
    for (int c = 0; c < C_; ++c) { float d = v[c] - mu; var += d * d; }
    var *= (1.0f / C_);
    float inv = rsqrtf(var + eps);
#pragma unroll
    for (int c = 0; c < C_; ++c)
        out[base + c * P_] = __float2bfloat16((v[c] - mu) * inv * swt[c] + sbt[c]);
}

// ---------------- fused per-pixel LN (eps 1e-6) + 1x1 projection -> bf16 ----------------
template <int COUT>
__global__ __launch_bounds__(256) void k_pwln(const float* __restrict__ Yin,
                                              const void* __restrict__ lnw, const void* __restrict__ lnb,
                                              const void* __restrict__ w,
                                              bf16* __restrict__ out,
                                              const int* __restrict__ dtf) {
    const bool bf = dtf[0] != 0;
    __shared__ bf16 swb[COUT * 64];
    __shared__ float slw[64], slb[64];
    for (int i = threadIdx.x; i < COUT * 64; i += 256) swb[i] = __float2bfloat16(ldin(w, i, bf));
    if (threadIdx.x < 64) {
        slw[threadIdx.x] = ldin(lnw, threadIdx.x, bf);
        slb[threadIdx.x] = ldin(lnb, threadIdx.x, bf);
    }
    __syncthreads();
    int g = blockIdx.x * 256 + threadIdx.x;
    int bb = g >> 16, p = g & (P_ - 1);
    int base = bb * 64 * P_ + p;
    float v[64];
    float mu = 0.f;
#pragma unroll
    for (int c = 0; c < 64; ++c) { v[c] = Yin[base + c * P_]; mu += v[c]; }
    mu *= (1.0f / 64.0f);
    float var = 0.f;
#pragma unroll
    for (int c = 0; c < 64; ++c) { float d = v[c] - mu; var += d * d; }
    float inv = rsqrtf(var * (1.0f / 64.0f) + 1e-6f);
#pragma unroll
    for (int c = 0; c < 64; ++c) v[c] = (v[c] - mu) * inv * slw[c] + slb[c];
    int obase = bb * COUT * P_ + p;
    const unsigned* uw = (const unsigned*)swb;
    for (int o = 0; o < COUT; ++o) {
        float a = 0.f;
#pragma unroll
        for (int cc = 0; cc < 32; ++cc) {
            float wa, wb;
            bf2x(uw[o * 32 + cc], wa, wb);
            a = fmaf(wa, v[2 * cc], fmaf(wb, v[2 * cc + 1], a));
        }
        out[obase + o * P_] = __float2bfloat16(a);
    }
}

// ---------------- MBConv dw3x3+gelu partial mean: 32 row-chunks per (b,c) plane ----------------
__global__ __launch_bounds__(256) void k_dwmean(const bf16* __restrict__ h,
                                                const void* __restrict__ dww,
                                                const void* __restrict__ dwb,
                                                float* __restrict__ part,
                                                const int* __restrict__ dtf) {
    const bool bf = dtf[0] != 0;
    __shared__ __align__(8) bf16 hsb[10 * 256];   // 5120 B
    __shared__ float red[256];
    int bid = blockIdx.x;
    int bc = bid >> 5, chunk = bid & 31;
    int c = bc & 63;
    int h0 = chunk * 8;
    int base = bc * P_;
    int tid = threadIdx.x;
    {
        const unsigned* gq = (const unsigned*)h;
        unsigned* hu = (unsigned*)hsb;
        for (int i = tid; i < 1280; i += 256) {
            int r = i >> 7, col2 = i & 127;
            int hh = h0 - 1 + r;
            unsigned v = 0u;
            if ((unsigned)hh < (unsigned)H_) v = gq[(base + hh * W_) / 2 + col2];
            hu[r * 128 + col2] = v;
        }
    }
    float w9[9];
#pragma unroll
    for (int k = 0; k < 9; ++k) w9[k] = ldin(dww, c * 9 + k, bf);
    float bv = ldin(dwb, c, bf);
    __syncthreads();
    float acc = 0.f;
#pragma unroll
    for (int k = 0; k < 8; ++k) {
        int j = tid + k * 256;          // 2048 px
        int r = j >> 8, x = j & 255;
        float s = bv;
#pragma unroll
        for (int kh = 0; kh < 3; ++kh) {
            const bf16* row = &hsb[(r + kh) * 256];
            float vm1 = (x > 0) ? cvt(row[x - 1]) : 0.f;
            float v0 = cvt(row[x]);
            float vp1 = (x < 255) ? cvt(row[x + 1]) : 0.f;
            s = fmaf(w9[kh * 3 + 0], vm1, s);
            s = fmaf(w9[kh * 3 + 1], v0, s);
            s = fmaf(w9[kh * 3 + 2], vp1, s);
        }
        acc += geluf(s);
    }
    red[tid] = acc;
    __syncthreads();
    for (int s2 = 128; s2 > 0; s2 >>= 1) {
        if (tid < s2) red[tid] += red[tid + s2];
        __syncthreads();
    }
    if (tid == 0) part[bc * 32 + chunk] = red[0];
}

// ---------------- SE MLP (reduces 32 partials per (b,c)) ----------------
__global__ __launch_bounds__(256) void k_se(const float* __restrict__ part,
                                            const void* __restrict__ w1,
                                            const void* __restrict__ w2,
                                            float* __restrict__ sfin,
                                            const int* __restrict__ dtf) {
    const bool bf = dtf[0] != 0;
    __shared__ float ssum[256];
    __shared__ float hbuf[B_ * 16];
    int t = threadIdx.x;
    {
        float a = 0.f;
#pragma unroll
        for (int k = 0; k < 32; ++k) a += part[t * 32 + k];
        ssum[t] = a * (1.0f / P_);
    }
    __syncthreads();
    if (t < B_ * 16) {
        int bb = t >> 4, j = t & 15;
        float a = 0.f;
        for (int c = 0; c < 64; ++c) a = fmaf(ssum[bb * 64 + c], ldin(w1, j * 64 + c, bf), a);
        hbuf[t] = a * sigm(a);
    }
    __syncthreads();
    int bb = t >> 6, c = t & 63;
    float a = 0.f;
    for (int j = 0; j < 16; ++j) a = fmaf(hbuf[bb * 16 + j], ldin(w2, c * 16 + j, bf), a);
    sfin[t] = sigm(a);
}

// ---------------- MBConv tail per window (R4 form): dw+gelu+scale -> 1x1 (tiled) -> += Y ---------
// div-free u32 staging (stride HSTR=61); dw weights in registers; staging overlapped with sw2T load
__global__ __launch_bounds__(256) void k_mb2w(const bf16* __restrict__ h,
                                              const void* __restrict__ dww, const void* __restrict__ dwb,
                                              const void* __restrict__ w2, const void* __restrict__ b2,
                                              const float* __restrict__ sfin,
                                              float* __restrict__ Y,
                                              const int* __restrict__ dtf) {
    const bool bf = dtf[0] != 0;
    __shared__ __align__(16) bf16 hs[64 * 2 * HSTR]; // 15616 B
    __shared__ __align__(16) bf16 ts[64 * 66];      // 8448 B
    __shared__ __align__(16) bf16 sw2T[64 * 64];    // 8192 B  [c][o]
    __shared__ float sdb[64], sb2[64], ssc[64];
    int wid = win_swz(blockIdx.x);
    int bb = wid >> 10;
    int h0 = ((wid >> 5) & 31) * 8, w0 = (wid & 31) * 8;
    int tid = threadIdx.x;
    int cch = tid >> 2, quarter = tid & 3;
    // stage halo: 64 ch x 60 u32 (stride 61), 4 threads/ch x 15, incremental addressing
    {
        const unsigned* gq = (const unsigned*)h;
        unsigned* hsu = (unsigned*)hs;
        int j = quarter * 15;
        int pr = j / 6, col = j - pr * 6;
        size_t chb = (size_t)(bb * 64 + cch) * P_;
        for (int k = 0; k < 15; ++k) {
            int hh = h0 + pr - 1;
            int wcx = w0 - 2 + 2 * col;
            unsigned v = 0u;
            if ((unsigned)hh < (unsigned)H_ && (unsigned)wcx < 255u)
                v = gq[(chb + hh * W_ + wcx) >> 1];
            hsu[cch * HSTR + j] = v;
            ++j; ++col;
            if (col == 6) { col = 0; ++pr; }
        }
    }
    float w9[9];
#pragma unroll
    for (int k = 0; k < 9; ++k) w9[k] = ldin(dww, cch * 9 + k, bf);
    for (int i = tid; i < 4096; i += 256) {
        int c = i >> 6, o = i & 63;
        sw2T[c * 64 + o] = __float2bfloat16(ldin(w2, o * 64 + c, bf));
    }
    if (tid < 64) {
        sdb[tid] = ldin(dwb, tid, bf);
        sb2[tid] = ldin(b2, tid, bf);
        ssc[tid] = sfin[bb * 64 + tid];
    }
    __syncthreads();
    // dw conv, pair-vectorized: channel cch, pairs p = quarter*8+k
    {
        const unsigned* mua = (const unsigned*)hs + cch * HSTR;
        unsigned* tsu = (unsigned*)ts;
        float bv = sdb[cch];
        float sc = ssc[cch];
#pragma unroll
        for (int k = 0; k < 8; ++k) {
            int p = quarter * 8 + k;
            int t0 = 2 * p;
            int rt = t0 >> 3, ct = t0 & 7;
            float a0 = bv, a1 = bv;
#pragma unroll
            for (int kh = 0; kh < 3; ++kh) {
                int rb = (rt + kh) * 6 + (ct >> 1);
                unsigned u0 = mua[rb], u1 = mua[rb + 1], u2 = mua[rb + 2];
                float x1 = bfhi(u0);
                float x2 = bflo(u1), x3 = bfhi(u1);
                float x4 = bflo(u2);
                a0 = fmaf(w9[kh * 3 + 0], x1, fmaf(w9[kh * 3 + 1], x2, fmaf(w9[kh * 3 + 2], x3, a0)));
                a1 = fmaf(w9[kh * 3 + 0], x2, fmaf(w9[kh * 3 + 1], x3, fmaf(w9[kh * 3 + 2], x4, a1)));
            }
            tsu[cch * 33 + p] = bfpack(geluf(a0) * sc, geluf(a1) * sc);
        }
    }
    __syncthreads();
    int og = tid >> 4, pg = tid & 15;
    int o0 = og * 4, p0 = pg * 4;
    float acc[4][4] = {};
    const unsigned* wt = (const unsigned*)sw2T;
    const unsigned* tt = (const unsigned*)ts;
    for (int c = 0; c < 64; ++c) {
        float w0v, w1v, w2v, w3v, t0, t1, t2, t3;
        bf2x(wt[c * 32 + (o0 >> 1)], w0v, w1v);
        bf2x(wt[c * 32 + (o0 >> 1) + 1], w2v, w3v);
        bf2x(tt[c * 33 + (p0 >> 1)], t0, t1);
        bf2x(tt[c * 33 + (p0 >> 1) + 1], t2, t3);
        acc[0][0] = fmaf(w0v, t0, acc[0][0]); acc[0][1] = fmaf(w0v, t1, acc[0][1]);
        acc[0][2] = fmaf(w0v, t2, acc[0][2]); acc[0][3] = fmaf(w0v, t3, acc[0][3]);
        acc[1][0] = fmaf(w1v, t0, acc[1][0]); acc[1][1] = fmaf(w1v, t1, acc[1][1]);
        acc[1][2] = fmaf(w1v, t2, acc[1][2]); acc[1][3] = fmaf(w1v, t3, acc[1][3]);
        acc[2][0] = fmaf(w2v, t0, acc[2][0]); acc[2][1] = fmaf(w2v, t1, acc[2][1]);
        acc[2][2] = fmaf(w2v, t2, acc[2][2]); acc[2][3] = fmaf(w2v, t3, acc[2][3]);
        acc[3][0] = fmaf(w3v, t0, acc[3][0]); acc[3][1] = fmaf(w3v, t1, acc[3][1]);
        acc[3][2] = fmaf(w3v, t2, acc[3][2]); acc[3][3] = fmaf(w3v, t3, acc[3][3]);
    }
#pragma unroll
    for (int i = 0; i < 4; ++i)
#pragma unroll
        for (int j = 0; j < 4; ++j) {
            int t = p0 + j;
            int p = (h0 + (t >> 3)) * W_ + w0 + (t & 7);
            Y[(bb * 64 + o0 + i) * P_ + p] += acc[i][j] + sb2[o0 + i];
        }
}

// ---------------- setup: compose Wq = qkvw @ q1w (fold 0.25 scale into q rows) ----------------
// WQT layout: [64 cin][96 out] bf16 ; BQ: f32[96] ; OWT: [32 cin][32 out] bf16
__global__ __launch_bounds__(256) void k_wprep(const void* __restrict__ q1w, const void* __restrict__ q1b,
                                               const void* __restrict__ qkvw, const void* __restrict__ outw,
                                               bf16* __restrict__ WQT, float* __restrict__ BQ,
                                               bf16* __restrict__ OWT,
                                               const int* __restrict__ dtf) {
    const bool bf = dtf[0] != 0;
    __shared__ float sq1[32 * 64];
    __shared__ float sqk[96 * 32];
    __shared__ float sb1[32];
    int tid = threadIdx.x;
    for (int i = tid; i < 2048; i += 256) sq1[i] = ldin(q1w, i, bf);
    for (int i = tid; i < 3072; i += 256) sqk[i] = ldin(qkvw, i, bf);
    if (tid < 32) sb1[tid] = ldin(q1b, tid, bf);
    __syncthreads();
    for (int idx = tid; idx < 6144; idx += 256) {
        int o = idx % 96, c = idx / 96;
        float a = 0.f;
        for (int k = 0; k < 32; ++k) a = fmaf(sqk[o * 32 + k], sq1[k * 64 + c], a);
        if (o < 32) a *= 0.25f;
        WQT[c * 96 + o] = __float2bfloat16(a);
    }
    if (tid < 96) {
        float a = 0.f;
        for (int k = 0; k < 32; ++k) a = fmaf(sqk[tid * 32 + k], sb1[k], a);
        if (tid < 32) a *= 0.25f;
        BQ[tid] = a;
    }
    for (int idx = tid; idx < 1024; idx += 256) {
        int o = idx >> 5, c = idx & 31;
        OWT[c * 32 + o] = __float2bfloat16(ldin(outw, o * 32 + c, bf));
    }
}

// ---------------- window self-attention (composed qkv, bf16 LDS, reg softmax) ----------------
__global__ __launch_bounds__(256, 4) void k_winattn(const bf16* __restrict__ xf,
                                                    const uint4* __restrict__ WQT,
                                                    const float* __restrict__ BQ,
                                                    const unsigned* __restrict__ OWT,
                                                    float* __restrict__ Y) {
    __shared__ __align__(16) char arena[35200];
    int wid = win_swz(blockIdx.x);
    int bb = wid >> 10;
    int h0 = ((wid >> 5) & 31) * 8, w0 = (wid & 31) * 8;
    int tid = threadIdx.x;
    // ---- stage composed weights + window (all bf16, vector ops) ----
    {
        uint4* sW4 = (uint4*)arena;
        for (int i = tid; i < 768; i += 256) sW4[i] = WQT[i];
        if (tid < 96) ((float*)(arena + 12288))[tid] = BQ[tid];
#pragma unroll
        for (int k = 0; k < 2; ++k) {
            int idx = tid + k * 256;          // 512 tasks: (c, window-row)
            int c = idx >> 3, r = idx & 7;
            const uint4 v = *(const uint4*)(xf + (size_t)(bb * 64 + c) * P_ + (h0 + r) * W_ + w0);
            *(uint4*)(arena + 12672 + c * 144 + r * 16) = v;
        }
    }
    __syncthreads();
    // ---- GEMM1: qkv[t][o] = bq[o] + sum_c W[c][o]*xf[c][t]  (96x64x64, 6x4 tiles) ----
    {
        const unsigned* uW = (const unsigned*)arena;
        const float* sbq = (const float*)(arena + 12288);
        const unsigned* uX = (const unsigned*)(arena + 12672);
        unsigned* uQw = (unsigned*)(arena + 21888);
        int og = tid >> 4, pg = tid & 15;     // o0 = og*6, t0 = pg*4
        float acc[6][4];
#pragma unroll
        for (int i = 0; i < 6; ++i) {
            float b = sbq[og * 6 + i];
#pragma unroll
            for (int j = 0; j < 4; ++j) acc[i][j] = b;
        }
        for (int c = 0; c < 64; ++c) {
            unsigned wu0 = uW[c * 48 + 3 * og];
            unsigned wu1 = uW[c * 48 + 3 * og + 1];
            unsigned wu2 = uW[c * 48 + 3 * og + 2];
            unsigned xu0 = uX[c * 36 + 2 * pg];
            unsigned xu1 = uX[c * 36 + 2 * pg + 1];
            float wv[6], xv[4];
            bf2x(wu0, wv[0], wv[1]); bf2x(wu1, wv[2], wv[3]); bf2x(wu2, wv[4], wv[5]);
            bf2x(xu0, xv[0], xv[1]); bf2x(xu1, xv[2], xv[3]);
#pragma unroll
            for (int i = 0; i < 6; ++i)
#pragma unroll
                for (int j = 0; j < 4; ++j) acc[i][j] = fmaf(wv[i], xv[j], acc[i][j]);
        }
#pragma unroll
        for (int j = 0; j < 4; ++j) {
            int t = pg * 4 + j;
#pragma unroll
            for (int k = 0; k < 3; ++k) {
                union { unsigned u; bf16 h[2]; } pk;
                pk.h[0] = __float2bfloat16(acc[2 * k][j]);
                pk.h[1] = __float2bfloat16(acc[2 * k + 1][j]);
                uQw[t * 52 + 3 * og + k] = pk.u;
            }
        }
    }
    __syncthreads();
    // ---- attention: wave = head, lane = token row; scores in registers ----
    {
        int hH = tid >> 6, lane = tid & 63;
        const unsigned* uQ = (const unsigned*)(arena + 21888);
        unsigned ow0 = OWT[tid * 2], ow1 = OWT[tid * 2 + 1];
        float qf[8];
        {
            const uint4 qv = *(const uint4*)&uQ[lane * 52 + hH * 4];
            bf2x(qv.x, qf[0], qf[1]); bf2x(qv.y, qf[2], qf[3]);
            bf2x(qv.z, qf[4], qf[5]); bf2x(qv.w, qf[6], qf[7]);
        }
        float p[64];
#pragma unroll
        for (int j = 0; j < 64; ++j) {
            const uint4 kv4 = *(const uint4*)&uQ[j * 52 + 16 + hH * 4];
            float kf[8];
            bf2x(kv4.x, kf[0], kf[1]); bf2x(kv4.y, kf[2], kf[3]);
            bf2x(kv4.z, kf[4], kf[5]); bf2x(kv4.w, kf[6], kf[7]);
            float s = 0.f;
#pragma unroll
            for (int d = 0; d < 8; ++d) s = fmaf(qf[d], kf[d], s);
            p[j] = s;
        }
        float m0 = fmaxf(p[0], p[4]), m1 = fmaxf(p[1], p[5]);
        float m2 = fmaxf(p[2], p[6]), m3 = fmaxf(p[3], p[7]);
#pragma unroll
        for (int j = 8; j < 64; j += 4) {
            m0 = fmaxf(m0, p[j]);     m1 = fmaxf(m1, p[j + 1]);
            m2 = fmaxf(m2, p[j + 2]); m3 = fmaxf(m3, p[j + 3]);
        }
        float mm = fmaxf(fmaxf(m0, m1), fmaxf(m2, m3));
        float s0 = 0.f, s1 = 0.f, s2 = 0.f, s3 = 0.f;
#pragma unroll
        for (int j = 0; j < 64; j += 4) {
            p[j] = __expf(p[j] - mm);         s0 += p[j];
            p[j + 1] = __expf(p[j + 1] - mm); s1 += p[j + 1];
            p[j + 2] = __expf(p[j + 2] - mm); s2 += p[j + 2];
            p[j + 3] = __expf(p[j + 3] - mm); s3 += p[j + 3];
        }
        float rs = 1.0f / ((s0 + s1) + (s2 + s3));
        float o[8] = {0.f, 0.f, 0.f, 0.f, 0.f, 0.f, 0.f, 0.f};
#pragma unroll
        for (int j = 0; j < 64; ++j) {
            const uint4 vv = *(const uint4*)&uQ[j * 52 + 32 + hH * 4];
            float vf[8];
            bf2x(vv.x, vf[0], vf[1]); bf2x(vv.y, vf[2], vf[3]);
            bf2x(vv.z, vf[4], vf[5]); bf2x(vv.w, vf[6], vf[7]);
#pragma unroll
            for (int d = 0; d < 8; ++d) o[d] = fmaf(p[j], vf[d], o[d]);
        }
        bf16* soa = (bf16*)(arena + 12672);
#pragma unroll
        for (int d = 0; d < 8; ++d)
            soa[(hH * 8 + d) * 68 + lane] = __float2bfloat16(o[d] * rs);
        unsigned* sow = (unsigned*)(arena + 17024);
        sow[tid * 2] = ow0; sow[tid * 2 + 1] = ow1;
    }
    __syncthreads();
    // ---- out projection 32x64x32 (2x4 tiles), += Y channels 0..31 ----
    {
        const unsigned* uOW = (const unsigned*)(arena + 17024);
        const unsigned* uOA = (const unsigned*)(arena + 12672);
        int og = tid >> 4, pg = tid & 15;     // o0 = og*2, t0 = pg*4
        float a2[2][4] = {};
        for (int c = 0; c < 32; ++c) {
            unsigned wu = uOW[c * 16 + og];
            unsigned a0 = uOA[c * 34 + 2 * pg], a1 = uOA[c * 34 + 2 * pg + 1];
            float wf0, wf1, x0, x1, x2, x3;
            bf2x(wu, wf0, wf1); bf2x(a0, x0, x1); bf2x(a1, x2, x3);
            a2[0][0] = fmaf(wf0, x0, a2[0][0]); a2[0][1] = fmaf(wf0, x1, a2[0][1]);
            a2[0][2] = fmaf(wf0, x2, a2[0][2]); a2[0][3] = fmaf(wf0, x3, a2[0][3]);
            a2[1][0] = fmaf(wf1, x0, a2[1][0]); a2[1][1] = fmaf(wf1, x1, a2[1][1]);
            a2[1][2] = fmaf(wf1, x2, a2[1][2]); a2[1][3] = fmaf(wf1, x3, a2[1][3]);
        }
#pragma unroll
        for (int i = 0; i < 2; ++i)
#pragma unroll
            for (int j = 0; j < 4; ++j) {
                int t = pg * 4 + j;
                int p2 = (h0 + (t >> 3)) * W_ + w0 + (t & 7);
                Y[((size_t)bb * 64 + og * 2 + i) * P_ + p2] += a2[i][j];
            }
    }
}

// ---------------- pointwise 1x1 conv (bf16 in -> bf16 out) ----------------
template <int CIN, int COUT>
__global__ __launch_bounds__(256) void k_pw(const bf16* __restrict__ in,
                                            const void* __restrict__ w,
                                            const void* __restrict__ bias,
                                            bf16* __restrict__ out,
                                            const int* __restrict__ dtf) {
    const bool bf = dtf[0] != 0;
    __shared__ float sw[COUT * CIN];
    __shared__ float sb[COUT];
    for (int i = threadIdx.x; i < COUT * CIN; i += 256) sw[i] = ldin(w, i, bf);
    if (threadIdx.x < COUT) sb[threadIdx.x] = bias ? ldin(bias, threadIdx.x, bf) : 0.f;
    __syncthreads();
    int g = blockIdx.x * 256 + threadIdx.x;
    int bb = g >> 16;
    int p = g & (P_ - 1);
    int ibase = bb * CIN * P_ + p;
    float v[CIN];
#pragma unroll
    for (int c = 0; c < CIN; ++c) v[c] = cvt(in[ibase + c * P_]);
    int obase = bb * COUT * P_ + p;
    for (int o = 0; o < COUT; ++o) {
        float acc = sb[o];
        const float* wr = &sw[o * CIN];
#pragma unroll
        for (int c = 0; c < CIN; ++c) acc = fmaf(wr[c], v[c], acc);
        out[obase + o * P_] = __float2bfloat16(acc);
    }
}

// ---------------- strided 3x3 conv (pad=1) ----------------
template <int CIN, int COUT, int OS, int STRIDE>
__global__ __launch_bounds__(256) void k_sconv(const bf16* __restrict__ in,
                                               const void* __restrict__ w,
                                               const void* __restrict__ bias,
                                               float* __restrict__ out,
                                               const int* __restrict__ dtf) {
    const bool bf = dtf[0] != 0;
    int g = blockIdx.x * 256 + threadIdx.x;
    int ow = g % OS;
    int oh = (g / OS) % OS;
    int oc = (g / (OS * OS)) % COUT;
    int bb = g / (OS * OS * COUT);
    float acc = ldin(bias, oc, bf);
    for (int ic = 0; ic < CIN; ++ic) {
        int ibase = (bb * CIN + ic) * P_;
        int wbase = (oc * CIN + ic) * 9;
#pragma unroll
        for (int kh = 0; kh < 3; ++kh) {
            int ih = oh * STRIDE + kh - 1;
            if ((unsigned)ih >= (unsigned)H_) continue;
#pragma unroll
            for (int kw = 0; kw < 3; ++kw) {
                int iw = ow * STRIDE + kw - 1;
                if ((unsigned)iw >= (unsigned)W_) continue;
                acc = fmaf(ldin(w, wbase + kh * 3 + kw, bf), cvt(in[ibase + ih * W_ + iw]), acc);
            }
        }
    }
    out[g] = acc;
}

// ---------------- sr-branch LN+gelu+kv ----------------
__global__ __launch_bounds__(64) void k_srkv(const float* __restrict__ x1,
                                             const void* __restrict__ lnw,
                                             const void* __restrict__ lnb,
                                             const void* __restrict__ kvw,
                                             const void* __restrict__ kvb,
                                             float* __restrict__ k1,
                                             float* __restrict__ v1,
                                             const int* __restrict__ dtf) {
    const bool bf = dtf[0] != 0;
    int tok = blockIdx.x;
    int bb = tok >> 8;
    int n = tok & 255;
    int c = threadIdx.x;
    __shared__ float sv[64];
    __shared__ float sg[64];
    float v = x1[(bb * 64 + c) * 256 + n];
    sv[c] = v;
    __syncthreads();
    float mu = 0.f;
    for (int i = 0; i < 64; ++i) mu += sv[i];
    mu *= (1.0f / 64.0f);
    float var = 0.f;
    for (int i = 0; i < 64; ++i) { float d = sv[i] - mu; var += d * d; }
    var *= (1.0f / 64.0f);
    float xn = (v - mu) * rsqrtf(var + 1e-5f) * ldin(lnw, c, bf) + ldin(lnb, c, bf);
    sg[c] = geluf(xn);
    __syncthreads();
    float acc = ldin(kvb, c, bf);
    for (int j = 0; j < 64; ++j) acc = fmaf(ldin(kvw, c * 64 + j, bf), sg[j], acc);
    int kk = c >> 5;
    int jh = (c >> 4) & 1;
    int d = c & 15;
    float* dst = kk ? v1 : k1;
    dst[((bb * 2 + jh) * 256 + n) * 16 + d] = acc;
}

// ---------------- low-res cross attention ----------------
__global__ __launch_bounds__(256) void k_xattn(const float* __restrict__ iqd,
                                               const float* __restrict__ k1,
                                               const float* __restrict__ v1,
                                               float* __restrict__ o1sp) {
    int bid = blockIdx.x;
    int iblk = bid & 3;
    int j = (bid >> 2) & 1;
    int bb = bid >> 3;
    __shared__ float sk[256 * 16];
    __shared__ float svv[256 * 16];
    int kbase = ((bb * 2 + j) * 256) * 16;
    for (int idx = threadIdx.x; idx < 4096; idx += 256) { sk[idx] = k1[kbase + idx]; svv[idx] = v1[kbase + idx]; }
    __syncthreads();
    int i = iblk * 256 + threadIdx.x;
    float q[16];
    int qbase = ((bb * 32 + (i >> 5)) * 32 + (i & 31)) * 32 + j * 16;
#pragma unroll
    for (int d = 0; d < 16; ++d) q[d] = iqd[qbase + d];
    float m = -1e30f, l = 0.f, o[16];
#pragma unroll
    for (int d = 0; d < 16; ++d) o[d] = 0.f;
    for (int n = 0; n < 256; ++n) {
        float s = 0.f;
#pragma unroll
        for (int d = 0; d < 16; ++d) s = fmaf(q[d], sk[n * 16 + d], s);
        s *= 0.25f;
        float mn = fmaxf(m, s);
        float corr = __expf(m - mn);
        float e = __expf(s - mn);
        l = l * corr + e;
#pragma unroll
        for (int d = 0; d < 16; ++d) o[d] = fmaf(o[d], corr, e * svv[n * 16 + d]);
        m = mn;
    }
    float r = 1.0f / l;
#pragma unroll
    for (int d = 0; d < 16; ++d)
        o1sp[((bb * 32 + j * 16 + d) * 32 + (i >> 5)) * 32 + (i & 31)] = o[d] * r;
}

// ---------------- cu conv (x8 upsample folded), += Y[32:64) ----------------
__global__ __launch_bounds__(256) void k_cuconv(const float* __restrict__ o1sp,
                                                const void* __restrict__ w,
                                                const void* __restrict__ bias,
                                                float* __restrict__ Y,
                                                const int* __restrict__ dtf) {
    const bool bf = dtf[0] != 0;
    __shared__ float sw[32 * 32 * 9];
    for (int i = threadIdx.x; i < 9216; i += 256) sw[i] = ldin(w, i, bf);
    __syncthreads();
    int g = blockIdx.x * 256 + threadIdx.x;
    int bb = g >> 16;
    int p = g & 65535;
    int h = p >> 8, x = p & 255;
    float acc[32];
#pragma unroll
    for (int oc = 0; oc < 32; ++oc) acc[oc] = ldin(bias, oc, bf);
    for (int ic = 0; ic < 32; ++ic) {
        int ibase = (bb * 32 + ic) * 1024;
        float v[9];
#pragma unroll
        for (int kh = 0; kh < 3; ++kh)
#pragma unroll
            for (int kw = 0; kw < 3; ++kw) {
                int hh = h + kh - 1, ww = x + kw - 1;
                v[kh * 3 + kw] = ((unsigned)hh < (unsigned)H_ && (unsigned)ww < (unsigned)W_)
                                     ? o1sp[ibase + (hh >> 3) * 32 + (ww >> 3)] : 0.f;
            }
        for (int oc = 0; oc < 32; ++oc) {
            const float* wr = &sw[(oc * 32 + ic) * 9];
            float a = acc[oc];
#pragma unroll
            for (int k = 0; k < 9; ++k) a = fmaf(wr[k], v[k], a);
            acc[oc] = a;
        }
    }
#pragma unroll
    for (int oc = 0; oc < 32; ++oc) Y[(bb * 64 + 32 + oc) * P_ + p] += acc[oc];
}

// ---------------- gcff tail (R4 form): u32 halo (stride 61), reg dw weights, paired dw+gate ------
__global__ __launch_bounds__(256) void k_gcff2(const bf16* __restrict__ mid_g,
                                               const void* __restrict__ dww,
                                               const void* __restrict__ outw,
                                               float* __restrict__ Y,
                                               const int* __restrict__ dtf) {
    const bool bf = dtf[0] != 0;
    __shared__ __align__(16) char arena[39680];
    bf16* mid = (bf16*)arena;               // [128][61 u32] = 31232 B
    bf16* ts = (bf16*)(arena + 31232);      // [64][66]   = 8448 B -> 39680
    bf16* sowT = (bf16*)arena;              // [c][o] 8192 B, overlays mid (dead)
    int wid = win_swz(blockIdx.x);
    int bb = wid >> 10;
    int h0 = ((wid >> 5) & 31) * 8, w0 = (wid & 31) * 8;
    int tid = threadIdx.x;
    // stage halo: 128 ch x 60 u32 (stride 61), 2 threads/ch x 30, incremental addressing
    {
        const unsigned* gq = (const unsigned*)mid_g;
        unsigned* mu = (unsigned*)mid;
        int c = tid >> 1, half = tid & 1;
        int j = half * 30;
        int pr = half * 5, col = 0;
        size_t chb = (size_t)(bb * 128 + c) * P_;
        for (int k = 0; k < 30; ++k) {
            int hh = h0 + pr - 1;
            int wcx = w0 - 2 + 2 * col;
            unsigned v = 0u;
            if ((unsigned)hh < (unsigned)H_ && (unsigned)wcx < 255u)
                v = gq[(chb + hh * W_ + wcx) >> 1];
            mu[c * HSTR + j] = v;
            ++j; ++col;
            if (col == 6) { col = 0; ++pr; }
        }
    }
    // dw weights to registers (a-branch ch cch, gate branch ch cch+64)
    int cch = tid >> 2, quarter = tid & 3;
    float wa9[9], wg9[9];
#pragma unroll
    for (int k = 0; k < 9; ++k) {
        wa9[k] = ldin(dww, cch * 9 + k, bf);
        wg9[k] = ldin(dww, (cch + 64) * 9 + k, bf);
    }
    __syncthreads();
    // dw conv + gate, pair-vectorized: channel cch, pairs p = quarter*8+k
    {
        const unsigned* mua = (const unsigned*)mid + cch * HSTR;
        const unsigned* mug = (const unsigned*)mid + (cch + 64) * HSTR;
        unsigned* tsu = (unsigned*)ts;
#pragma unroll
        for (int k = 0; k < 8; ++k) {
            int p = quarter * 8 + k;
            int t0 = 2 * p;
            int rt = t0 >> 3, ct = t0 & 7;
            float a0 = 0.f, a1 = 0.f, g0 = 0.f, g1 = 0.f;
#pragma unroll
            for (int kh = 0; kh < 3; ++kh) {
                int rb = (rt + kh) * 6 + (ct >> 1);
                unsigned ua0 = mua[rb], ua1 = mua[rb + 1], ua2 = mua[rb + 2];
                unsigned ug0 = mug[rb], ug1 = mug[rb + 1], ug2 = mug[rb + 2];
                float x1 = bfhi(ua0);
                float x2 = bflo(ua1), x3 = bfhi(ua1);
                float x4 = bflo(ua2);
                a0 = fmaf(wa9[kh * 3 + 0], x1, fmaf(wa9[kh * 3 + 1], x2, fmaf(wa9[kh * 3 + 2], x3, a0)));
                a1 = fmaf(wa9[kh * 3 + 0], x2, fmaf(wa9[kh * 3 + 1], x3, fmaf(wa9[kh * 3 + 2], x4, a1)));
                float y1 = bfhi(ug0);
                float y2 = bflo(ug1), y3 = bfhi(ug1);
                float y4 = bflo(ug2);
                g0 = fmaf(wg9[kh * 3 + 0], y1, fmaf(wg9[kh * 3 + 1], y2, fmaf(wg9[kh * 3 + 2], y3, g0)));
                g1 = fmaf(wg9[kh * 3 + 0], y2, fmaf(wg9[kh * 3 + 1], y3, fmaf(wg9[kh * 3 + 2], y4, g1)));
            }
            tsu[cch * 33 + p] = bfpack(geluf(a0) * g0, geluf(a1) * g1);
        }
    }
    __syncthreads();
    for (int i = tid; i < 4096; i += 256) {
        int c = i >> 6, o = i & 63;
        sowT[c * 64 + o] = __float2bfloat16(ldin(outw, o * 64 + c, bf));
    }
    __syncthreads();
    int og = tid >> 4, pg = tid & 15;
    int o0 = og * 4, p0 = pg * 4;
    float acc[4][4] = {};
    const unsigned* wt = (const unsigned*)sowT;
    const unsigned* tt = (const unsigned*)ts;
    for (int c = 0; c < 64; ++c) {
        float w0v, w1v, w2v, w3v, t0, t1, t2, t3;
        bf2x(wt[c * 32 + (o0 >> 1)], w0v, w1v);
        bf2x(wt[c * 32 + (o0 >> 1) + 1], w2v, w3v);
        bf2x(tt[c * 33 + (p0 >> 1)], t0, t1);
        bf2x(tt[c * 33 + (p0 >> 1) + 1], t2, t3);
        acc[0][0] = fmaf(w0v, t0, acc[0][0]); acc[0][1] = fmaf(w0v, t1, acc[0][1]);
        acc[0][2] = fmaf(w0v, t2, acc[0][2]); acc[0][3] = fmaf(w0v, t3, acc[0][3]);
        acc[1][0] = fmaf(w1v, t0, acc[1][0]); acc[1][1] = fmaf(w1v, t1, acc[1][1]);
        acc[1][2] = fmaf(w1v, t2, acc[1][2]); acc[1][3] = fmaf(w1v, t3, acc[1][3]);
        acc[2][0] = fmaf(w2v, t0, acc[2][0]); acc[2][1] = fmaf(w2v, t1, acc[2][1]);
        acc[2][2] = fmaf(w2v, t2, acc[2][2]); acc[2][3] = fmaf(w2v, t3, acc[2][3]);
        acc[3][0] = fmaf(w3v, t0, acc[3][0]); acc[3][1] = fmaf(w3v, t1, acc[3][1]);
        acc[3][2] = fmaf(w3v, t2, acc[3][2]); acc[3][3] = fmaf(w3v, t3, acc[3][3]);
    }
#pragma unroll
    for (int i = 0; i < 4; ++i)
#pragma unroll
        for (int j = 0; j < 4; ++j) {
            int t = p0 + j;
            int p = (h0 + (t >> 3)) * W_ + w0 + (t & 7);
            Y[(bb * 64 + o0 + i) * P_ + p] += acc[i][j];
        }
}

// ---------------- channel attention: reg-prefetched halo chunks, fused shfl L2-norm, 40960 B -----
__global__ __launch_bounds__(256) void k_chattn2(const bf16* __restrict__ qkv_g,
                                                 const void* __restrict__ dww,
                                                 const void* __restrict__ outw,
                                                 const void* __restrict__ tempw,
                                                 float* __restrict__ Y,
                                                 const int* __restrict__ dtf) {
    const bool bf = dtf[0] != 0;
    __shared__ __align__(16) char arena[40960];
    bf16* sq = (bf16*)arena;                 // [192][66] = 25344
    bf16* chunkb = (bf16*)(arena + 25344);   // [64][61 u32] = 15616 -> 40960
    bf16* s_owT = (bf16*)arena;              // [c][o] 8192, overlays q-rows (dead after s_att)
    float* s_att = (float*)(arena + 25344);  // [64][17] = 4352 (overlay chunkb)
    bf16* s_oc = (bf16*)(arena + 29696);     // [64][66] = 8448 (end 38144 < 40960)
    int wid = win_swz(blockIdx.x);
    int bb = wid >> 10;
    int h0 = ((wid >> 5) & 31) * 8, w0 = (wid & 31) * 8;
    int tid = threadIdx.x;
    int cch = tid >> 2, quarter = tid & 3;
    const unsigned* gq = (const unsigned*)qkv_g;
    unsigned* cbu = (unsigned*)chunkb;
    unsigned* squ = (unsigned*)sq;
    int j0 = quarter * 15;
    int pr0 = j0 / 6, col0 = j0 - pr0 * 6;
    unsigned regs[15];
    // preload chunk 0 halo into registers
    {
        int pr = pr0, col = col0;
        size_t chb = (size_t)((bb * 192 + cch) * P_);
#pragma unroll
        for (int k = 0; k < 15; ++k) {
            int hh = h0 + pr - 1;
            int wcx = w0 - 2 + 2 * col;
            unsigned v = 0u;
            if ((unsigned)hh < (unsigned)H_ && (unsigned)wcx < 255u)
                v = gq[(chb + hh * W_ + wcx) >> 1];
            regs[k] = v;
            ++col; if (col == 6) { col = 0; ++pr; }
        }
    }
    for (int chunk = 0; chunk < 3; ++chunk) {
        int ch0 = chunk * 64;
        // write staged registers to halo LDS
#pragma unroll
        for (int k = 0; k < 15; ++k) cbu[cch * HSTR + j0 + k] = regs[k];
        float w9[9];
#pragma unroll
        for (int k = 0; k < 9; ++k) w9[k] = ldin(dww, (ch0 + cch) * 9 + k, bf);
        __syncthreads();
        // prefetch next chunk's halo into registers (hidden under conv)
        if (chunk < 2) {
            int pr = pr0, col = col0;
            size_t chb = (size_t)((bb * 192 + ch0 + 64 + cch) * P_);
#pragma unroll
            for (int k = 0; k < 15; ++k) {
                int hh = h0 + pr - 1;
                int wcx = w0 - 2 + 2 * col;
                unsigned v = 0u;
                if ((unsigned)hh < (unsigned)H_ && (unsigned)wcx < 255u)
                    v = gq[(chb + hh * W_ + wcx) >> 1];
                regs[k] = v;
                ++col; if (col == 6) { col = 0; ++pr; }
            }
        }
        // dw conv into registers; fused L2-normalize for q/k chunks via 4-lane shfl reduce
        {
            const unsigned* mua = cbu + cch * HSTR;
            float vals[16];
            float ss = 0.f;
#pragma unroll
            for (int k = 0; k < 8; ++k) {
                int p = quarter * 8 + k;
                int t0 = 2 * p;
                int rt = t0 >> 3, ct = t0 & 7;
                float a0 = 0.f, a1 = 0.f;
#pragma unroll
                for (int kh = 0; kh < 3; ++kh) {
                    int rb = (rt + kh) * 6 + (ct >> 1);
                    unsigned u0 = mua[rb], u1 = mua[rb + 1], u2 = mua[rb + 2];
                    float x1 = bfhi(u0);
                    float x2 = bflo(u1), x3 = bfhi(u1);
                    float x4 = bflo(u2);
                    a0 = fmaf(w9[kh * 3 + 0], x1, fmaf(w9[kh * 3 + 1], x2, fmaf(w9[kh * 3 + 2], x3, a0)));
                    a1 = fmaf(w9[kh * 3 + 0], x2, fmaf(w9[kh * 3 + 1], x3, fmaf(w9[kh * 3 + 2], x4, a1)));
                }
                vals[2 * k] = a0; vals[2 * k + 1] = a1;
                ss = fmaf(a0, a0, fmaf(a1, a1, ss));
            }
            if (chunk < 2) {   // q and k rows: L2-normalize across the 4 owning lanes
                ss += __shfl_xor(ss, 1);
                ss += __shfl_xor(ss, 2);
                float inv = 1.0f / fmaxf(sqrtf(ss), 1e-12f);
#pragma unroll
                for (int k = 0; k < 16; ++k) vals[k] *= inv;
            }
#pragma unroll
            for (int k = 0; k < 8; ++k)
                squ[(ch0 + cch) * 33 + quarter * 8 + k] = bfpack(vals[2 * k], vals[2 * k + 1]);
        }
        __syncthreads();
    }
    // s_att = (q . k) * temp  (vectorized along t)
    for (int i = tid; i < 1024; i += 256) {
        int hh = i >> 8, d = (i >> 4) & 15, f = i & 15;
        const unsigned* qrow = squ + (hh * 16 + d) * 33;
        const unsigned* krow = squ + (64 + hh * 16 + f) * 33;
        float acc = 0.f;
#pragma unroll
        for (int t2 = 0; t2 < 32; ++t2) {
            float q0, q1, k0, k1;
            bf2x(qrow[t2], q0, q1);
            bf2x(krow[t2], k0, k1);
            acc = fmaf(q0, k0, fmaf(q1, k1, acc));
        }
        s_att[(hh * 16 + d) * 17 + f] = acc * ldin(tempw, hh, bf);
    }
    __syncthreads();
    if (tid < 64) {
        int row = tid;
        float m = -1e30f;
        for (int f = 0; f < 16; ++f) m = fmaxf(m, s_att[row * 17 + f]);
        float sum = 0.f;
        for (int f = 0; f < 16; ++f) { float e = __expf(s_att[row * 17 + f] - m); s_att[row * 17 + f] = e; sum += e; }
        float r = 1.0f / sum;
        for (int f = 0; f < 16; ++f) s_att[row * 17 + f] *= r;
    }
    __syncthreads();
    // PV, pair-vectorized along t (reads V rows only) + owT load into dead q-row space
    {
        unsigned* s_ocu = (unsigned*)s_oc;
        for (int i = tid; i < 2048; i += 256) {
            int row = i >> 5, p = i & 31;
            int hh = row >> 4, d = row & 15;
            const float* arow = &s_att[(hh * 16 + d) * 17];
            float o0 = 0.f, o1 = 0.f;
#pragma unroll
            for (int f = 0; f < 16; ++f) {
                float av = arow[f];
                float v0, v1;
                bf2x(squ[(128 + hh * 16 + f) * 33 + p], v0, v1);
                o0 = fmaf(av, v0, o0);
                o1 = fmaf(av, v1, o1);
            }
            s_ocu[row * 33 + p] = bfpack(o0, o1);
        }
        for (int i = tid; i < 4096; i += 256) {
            int c = i >> 6, o = i & 63;
            s_owT[c * 64 + o] = __float2bfloat16(ldin(outw, o * 64 + c, bf));
        }
    }
    __syncthreads();
    int og = tid >> 4, pg = tid & 15;
    int o0 = og * 4, p0 = pg * 4;
    float acc[4][4] = {};
    const unsigned* wt = (const unsigned*)s_owT;
    const unsigned* tt = (const unsigned*)s_oc;
    for (int c = 0; c < 64; ++c) {
        float w0v, w1v, w2v, w3v, t0, t1, t2, t3;
        bf2x(wt[c * 32 + (o0 >> 1)], w0v, w1v);
        bf2x(wt[c * 32 + (o0 >> 1) + 1], w2v, w3v);
        bf2x(tt[c * 33 + (p0 >> 1)], t0, t1);
        bf2x(tt[c * 33 + (p0 >> 1) + 1], t2, t3);
        acc[0][0] = fmaf(w0v, t0, acc[0][0]); acc[0][1] = fmaf(w0v, t1, acc[0][1]);
        acc[0][2] = fmaf(w0v, t2, acc[0][2]); acc[0][3] = fmaf(w0v, t3, acc[0][3]);
        acc[1][0] = fmaf(w1v, t0, acc[1][0]); acc[1][1] = fmaf(w1v, t1, acc[1][1]);
        acc[1][2] = fmaf(w1v, t2, acc[1][2]); acc[1][3] = fmaf(w1v, t3, acc[1][3]);
        acc[2][0] = fmaf(w2v, t0, acc[2][0]); acc[2][1] = fmaf(w2v, t1, acc[2][1]);
        acc[2][2] = fmaf(w2v, t2, acc[2][2]); acc[2][3] = fmaf(w2v, t3, acc[2][3]);
        acc[3][0] = fmaf(w3v, t0, acc[3][0]); acc[3][1] = fmaf(w3v, t1, acc[3][1]);
        acc[3][2] = fmaf(w3v, t2, acc[3][2]); acc[3][3] = fmaf(w3v, t3, acc[3][3]);
    }
#pragma unroll
    for (int i = 0; i < 4; ++i)
#pragma unroll
        for (int j = 0; j < 4; ++j) {
            int t = p0 + j;
            int p = (h0 + (t >> 3)) * W_ + w0 + (t & 7);
            Y[(bb * 64 + o0 + i) * P_ + p] += acc[i][j];
        }
}

// ---------------- final 1x1 over concat([x, y]) -> adaptive dtype out ----------------
__global__ __launch_bounds__(256) void k_final(const void* __restrict__ x,
                                               const float* __restrict__ Yb,
                                               const void* __restrict__ w,
                                               const void* __restrict__ bias,
                                               void* __restrict__ out,
                                               const int* __restrict__ dtf) {
    const bool bf = dtf[0] != 0;
    __shared__ float sw[64 * 128];
    __shared__ float sb[64];
    for (int i = threadIdx.x; i < 8192; i += 256) sw[i] = ldin(w, i, bf);
    if (threadIdx.x < 64) sb[threadIdx.x] = ldin(bias, threadIdx.x, bf);
    __syncthreads();
    int g = blockIdx.x * 256 + threadIdx.x;
    int bb = g >> 16;
    int p = g & 65535;
    float xv[64], yv[64];
    int base = bb * 64 * P_ + p;
#pragma unroll
    for (int c = 0; c < 64; ++c) xv[c] = ldin(x, base + c * P_, bf);
#pragma unroll
    for (int c = 0; c < 64; ++c) yv[c] = Yb[base + c * P_];
    for (int o = 0; o < 64; ++o) {
        float acc = sb[o];
        const float* wr = &sw[o * 128];
#pragma unroll
        for (int c = 0; c < 64; ++c) acc = fmaf(wr[c], xv[c], acc);
#pragma unroll
        for (int c = 0; c < 64; ++c) acc = fmaf(wr[64 + c], yv[c], acc);
        if (bf) ((bf16*)out)[base + o * P_] = __float2bfloat16(acc);
        else    ((float*)out)[base + o * P_] = acc;
    }
}

extern "C" void kernel_launch(void* const* d_in, const int* in_sizes, int n_in,
                              void* d_out, int out_size, void* d_ws, size_t ws_size,
                              hipStream_t stream) {
    const void* x        = d_in[0];
    const void* norm_w   = d_in[1];
    const void* norm_b   = d_in[2];
    const void* conv1_w  = d_in[3];
    const void* conv1_b  = d_in[4];
    const void* conv2_w  = d_in[5];
    const void* conv2_b  = d_in[6];
    const void* mb_w1    = d_in[7];
    const void* mb_b1    = d_in[8];
    const void* mb_dw_w  = d_in[9];
    const void* mb_dw_b  = d_in[10];
    const void* se_w1    = d_in[11];
    const void* se_w2    = d_in[12];
    const void* mb_w2    = d_in[13];
    const void* mb_b2    = d_in[14];
    const void* ln_att_w = d_in[15];
    const void* ln_att_b = d_in[16];
    const void* q1_w     = d_in[17];
    const void* q1_b     = d_in[18];
    const void* qkv_w    = d_in[19];
    const void* to_out_w = d_in[20];
    const void* sr_w     = d_in[21];
    const void* sr_b     = d_in[22];
    const void* ln_sr_w  = d_in[23];
    const void* ln_sr_b  = d_in[24];
    const void* kv1_w    = d_in[25];
    const void* kv1_b    = d_in[26];
    const void* q2_w     = d_in[27];
    const void* q2_b     = d_in[28];
    const void* cd_w     = d_in[29];
    const void* cd_b     = d_in[30];
    const void* cu_w     = d_in[31];
    const void* cu_b     = d_in[32];
    const void* cln1_w   = d_in[33];
    const void* cln1_b   = d_in[34];
    const void* ff1_in_w = d_in[35];
    const void* ff1_dw_w = d_in[36];
    const void* ff1_out_w= d_in[37];
    const void* cln2_w   = d_in[38];
    const void* cln2_b   = d_in[39];
    const void* ca_temp  = d_in[40];
    const void* ca_qkv_w = d_in[41];
    const void* ca_dw_w  = d_in[42];
    const void* ca_out_w = d_in[43];
    const void* cln3_w   = d_in[44];
    const void* cln3_b   = d_in[45];
    const void* ff2_in_w = d_in[46];
    const void* ff2_dw_w = d_in[47];
    const void* ff2_out_w= d_in[48];

    // Workspace: smalls @0, Y @2M (64M), T1 @66M (32M), IQ @98M (16M), MID/QKV @114M (96M) -> 210M peak
    char* ws = (char*)d_ws;
    int*   dtf   = (int*)ws;
    float* s_fin = (float*)(ws + 8192);
    bf16*  WQT   = (bf16*)(ws + 16384);   // 64x96 bf16 composed qkv weight [c][o], 12288 B
    float* BQc   = (float*)(ws + 28672);  // 96 f32 composed bias, 384 B
    bf16*  OWT   = (bf16*)(ws + 29056);   // 32x32 bf16 out-proj [c][o], 2048 B
    float* part  = (float*)(ws + 32768);  // 256x32 dwmean partials, 32768 B
    float* iqd   = (float*)(ws + 65536);
    float* x1    = (float*)(ws + 589824);
    float* k1b   = (float*)(ws + 851968);
    float* v1b   = (float*)(ws + 983040);
    float* o1sp  = (float*)(ws + 1114112);
    float* Y     = (float*)(ws + 2097152);
    bf16*  T1    = (bf16*)(ws + 69206016);
    bf16*  IQ    = (bf16*)(ws + 102760448);
    bf16*  MIDQ  = (bf16*)(ws + 119537664);

    dim3 blk(256);
    dim3 gPix(NP_ / 256);    // 1024
    dim3 gWin(B_ * 32 * 32); // 4096

    k_detect<<<dim3(1), blk, 0, stream>>>((const unsigned int*)x, dtf);
    // compose window-attn weights (tiny, once)
    k_wprep<<<dim3(1), blk, 0, stream>>>(q1_w, q1_b, qkv_w, to_out_w, WQT, BQc, OWT, dtf);
    // LN + conv1 -> Y ; mb1+gelu -> T1
    k_head<<<gPix, blk, 0, stream>>>(x, norm_w, norm_b, conv1_w, conv1_b, mb_w1, mb_b1, Y, T1, dtf);
    // MBConv SE + tail
    k_dwmean<<<dim3(B_ * C_ * 32), blk, 0, stream>>>(T1, mb_dw_w, mb_dw_b, part, dtf);
    k_se<<<dim3(1), blk, 0, stream>>>(part, se_w1, se_w2, s_fin, dtf);
    k_mb2w<<<gWin, blk, 0, stream>>>(T1, mb_dw_w, mb_dw_b, mb_w2, mb_b2, s_fin, Y, dtf);
    // hybrid attention
    k_ln<<<gPix, blk, 0, stream>>>(Y, ln_att_w, ln_att_b, T1, 1e-5f, dtf);
    k_winattn<<<gWin, blk, 0, stream>>>(T1, (const uint4*)WQT, BQc, (const unsigned*)OWT, Y);
    // cross-attn branch
    k_pw<64, 32><<<gPix, blk, 0, stream>>>(T1, q2_w, q2_b, IQ, dtf);
    k_sconv<32, 32, 32, 8><<<dim3(512), blk, 0, stream>>>(IQ, cd_w, cd_b, iqd, dtf);
    k_sconv<64, 64, 16, 16><<<dim3(256), blk, 0, stream>>>(T1, sr_w, sr_b, x1, dtf);
    k_srkv<<<dim3(B_ * 256), dim3(64), 0, stream>>>(x1, ln_sr_w, ln_sr_b, kv1_w, kv1_b, k1b, v1b, dtf);
    k_xattn<<<dim3(32), blk, 0, stream>>>(iqd, k1b, v1b, o1sp);
    k_cuconv<<<gPix, blk, 0, stream>>>(o1sp, cu_w, cu_b, Y, dtf);
    // gcff #1 (fused LN + in-proj, then window tail)
    k_pwln<128><<<gPix, blk, 0, stream>>>(Y, cln1_w, cln1_b, ff1_in_w, MIDQ, dtf);
    k_gcff2<<<gWin, blk, 0, stream>>>(MIDQ, ff1_dw_w, ff1_out_w, Y, dtf);
    // channel attention (fused LN + qkv-proj, then window tail)
    k_pwln<192><<<gPix, blk, 0, stream>>>(Y, cln2_w, cln2_b, ca_qkv_w, MIDQ, dtf);
    k_chattn2<<<gWin, blk, 0, stream>>>(MIDQ, ca_dw_w, ca_out_w, ca_temp, Y, dtf);
    // gcff #2
    k_pwln<128><<<gPix, blk, 0, stream>>>(Y, cln3_w, cln3_b, ff2_in_w, MIDQ, dtf);
    k_gcff2<<<gWin, blk, 0, stream>>>(MIDQ, ff2_dw_w, ff2_out_w, Y, dtf);
    // fuse with block input
    k_final<<<gPix, blk, 0, stream>>>(x, Y, conv2_w, conv2_b, d_out, dtf);

    (void)in_sizes; (void)n_in; (void)out_size; (void)ws_size;
}